// Round 6
// baseline (533.047 us; speedup 1.0000x reference)
//
#include <hip/hip_runtime.h>

#define HDIM 768
#define SDIM 4096
#define BATCH 8
#define NSPAN 8192
#define TK 50
#define WDIM 30
#define NW 11
#define PHID 150
#define FDIM 1566
#define FPAD 1568
#define NBLK 512
#define LSTR 40           // LDS GEMM row stride (shorts)
#define SURV_CAP 2048

typedef short  bf16x8 __attribute__((ext_vector_type(8)));
typedef unsigned short u16x8 __attribute__((ext_vector_type(8)));
typedef float  f32x4  __attribute__((ext_vector_type(4)));

__device__ __forceinline__ float b2f(unsigned short u) {
  union { unsigned int i; float f; } x; x.i = (unsigned int)u << 16; return x.f;
}
__device__ __forceinline__ unsigned short f2b(float f) {
  union { float f; unsigned int i; } x; x.f = f;
  unsigned int u = x.i;
  return (unsigned short)((u + 0x7fffu + ((u >> 16) & 1u)) >> 16);
}
__device__ __forceinline__ int aload(int* p) {
  return __hip_atomic_load(p, __ATOMIC_RELAXED, __HIP_MEMORY_SCOPE_AGENT);
}
__device__ __forceinline__ void astore(int* p, int v) {
  __hip_atomic_store(p, v, __ATOMIC_RELAXED, __HIP_MEMORY_SCOPE_AGENT);
}

// garbage-immune grid barrier: exact-match flags + generation; bounded spins (no hang).
__device__ void gbar(int* flg, int* gen, int k, int blk) {
  __syncthreads();
  if (blk == 0) {
    if (threadIdx.x == 0) __threadfence();
    __syncthreads();
    for (int j = 1 + (int)threadIdx.x; j < NBLK; j += 256) {
      int tries = 0;
      while (aload(&flg[j]) != 1000 + k) {
        if (++tries > (1 << 22)) break;
        __builtin_amdgcn_s_sleep(2);
      }
    }
    __syncthreads();
    if (threadIdx.x == 0) { __threadfence(); astore(gen, k + 1); __threadfence(); }
    __syncthreads();
  } else {
    if (threadIdx.x == 0) {
      __threadfence();
      astore(&flg[blk], 1000 + k);
      int tries = 0;
      while (aload(gen) != k + 1) {
        if (++tries > (1 << 22)) break;
        __builtin_amdgcn_s_sleep(2);
      }
      __threadfence();
    }
    __syncthreads();
  }
}

// ============================ the mega kernel ============================
__global__ __launch_bounds__(256, 2) void k_mega(
    const float* __restrict__ seq, const int* __restrict__ sp_st, const int* __restrict__ sp_en,
    const float* __restrict__ W_start, const float* __restrict__ b_start,
    const float* __restrict__ W_end, const float* __restrict__ b_end,
    const float* __restrict__ wemb, const float* __restrict__ W_out,
    const float* __restrict__ b_out, const float* __restrict__ w_men,
    const float* __restrict__ b_men, const float* __restrict__ W_p1,
    const float* __restrict__ b_p1, const float* __restrict__ ln_g,
    const float* __restrict__ ln_b, const float* __restrict__ W_p2,
    const float* __restrict__ b_p2, float* __restrict__ out, char* __restrict__ ws) {
  // ---- workspace layout ----
  constexpr size_t OFF_FLG = 0;                              // int[512]
  constexpr size_t OFF_GEN = OFF_FLG + 512 * 4;              // int (pad 16)
  constexpr size_t OFF_U   = OFF_GEN + 16;                   // double[1568]
  constexpr size_t OFF_VS  = OFF_U   + 1568 * 8;             // float[768]
  constexpr size_t OFF_VE  = OFF_VS  + 768 * 4;              // float[768]
  constexpr size_t OFF_MWC = OFF_VE  + 768 * 4;              // double[16]
  constexpr size_t OFF_MS  = OFF_MWC + 16 * 8;               // double[32768]
  constexpr size_t OFF_ME  = OFF_MS  + 32768 * 8;            // double[32768]
  constexpr size_t OFF_SS  = OFF_ME  + 32768 * 8;            // int[512]
  constexpr size_t OFF_SE  = OFF_SS  + 512 * 4;              // int[512]
  constexpr size_t OFF_SW  = OFF_SE  + 512 * 4;              // int[512]
  constexpr size_t OFF_W3  = OFF_SW  + 512 * 4;              // float[11*768]
  constexpr size_t OFF_WOT = OFF_W3  + 11 * 768 * 4;         // u16[768*1568]
  constexpr size_t OFF_WCT = OFF_WOT + (size_t)768 * FPAD * 2; // u16[320*768]
  constexpr size_t OFF_WPD = OFF_WCT + (size_t)320 * 768 * 2;  // u16[160*768]
  constexpr size_t OFF_B1  = OFF_WPD + (size_t)160 * 768 * 2;  // u16[768*768]
  constexpr size_t OFF_B2  = OFF_B1  + (size_t)768 * 768 * 2;  // u16[768*768]
  constexpr size_t OFF_RB  = OFF_B2  + (size_t)768 * 768 * 2;  // u16[400*768]
  constexpr size_t OFF_PC  = OFF_RB  + (size_t)400 * 768 * 2;  // f32[400*300]

  int* flg = (int*)(ws + OFF_FLG);
  int* gen = (int*)(ws + OFF_GEN);
  double* u    = (double*)(ws + OFF_U);
  float*  vs   = (float*)(ws + OFF_VS);
  float*  ve   = (float*)(ws + OFF_VE);
  double* mwc  = (double*)(ws + OFF_MWC);
  double* ms   = (double*)(ws + OFF_MS);
  double* me   = (double*)(ws + OFF_ME);
  int* sel_s   = (int*)(ws + OFF_SS);
  int* sel_e   = (int*)(ws + OFF_SE);
  int* sel_w   = (int*)(ws + OFF_SW);
  float* W3    = (float*)(ws + OFF_W3);
  unsigned short* Wot = (unsigned short*)(ws + OFF_WOT);
  unsigned short* Wct = (unsigned short*)(ws + OFF_WCT);
  unsigned short* Wpd = (unsigned short*)(ws + OFF_WPD);
  unsigned short* Bt1 = (unsigned short*)(ws + OFF_B1);
  unsigned short* Bt2 = (unsigned short*)(ws + OFF_B2);
  unsigned short* Rb  = (unsigned short*)(ws + OFF_RB);
  float* Pcat  = (float*)(ws + OFF_PC);

  __shared__ __align__(16) char smem[26624];
  int blk = blockIdx.x, t = threadIdx.x;
  int wv = t >> 6, lane = t & 63, quad = lane >> 4, coll = lane & 15;
  int rs = t >> 2, ch = t & 3;

  // ================= P0: Wot transpose, Wct/Wpd, u, W3 =================
  {
    float (*Tl)[33] = (float (*)[33])smem;
    int rr = t >> 5, cc = t & 31;
    for (int j = blk; j < 49 * 24; j += NBLK) {
      int k0 = (j % 49) * 32, n0 = (j / 49) * 32;
      #pragma unroll
      for (int q = 0; q < 4; ++q) {
        int kr = rr + q * 8, kk = k0 + kr, nn = n0 + cc;
        Tl[kr][cc] = (kk < FDIM) ? W_out[(size_t)kk * HDIM + nn] : 0.f;
      }
      __syncthreads();
      #pragma unroll
      for (int q = 0; q < 4; ++q) {
        int nr = rr + q * 8;
        Wot[(size_t)(n0 + nr) * FPAD + k0 + cc] = f2b(Tl[cc][nr]);
      }
      __syncthreads();
    }
  }
  for (int idx = blk * 256 + t; idx < 480 * HDIM; idx += NBLK * 256) {
    if (idx < 320 * HDIM) {
      int n = idx / HDIM, h = idx % HDIM;
      float v = 0.f;
      if (n < PHID)      v = W_p1[(size_t)h * PHID + n] + W_p1[(size_t)(2 * HDIM + h) * PHID + n];
      else if (n < 300)  v = W_p1[(size_t)(HDIM + h) * PHID + (n - PHID)] -
                             W_p1[(size_t)(2 * HDIM + h) * PHID + (n - PHID)];
      Wct[idx] = f2b(v);
    } else {
      int j = idx - 320 * HDIM;
      int n = j / HDIM, h = j % HDIM;
      Wpd[j] = f2b((n < PHID) ? W_p1[(size_t)(3 * HDIM + h) * PHID + n] : 0.f);
    }
  }
  {
    int wg = blk * 4 + wv;
    if (wg < FDIM) {
      const float* Wrow = W_out + (size_t)wg * HDIM;
      double acc = 0.0;
      for (int c = lane; c < HDIM; c += 64) acc += (double)Wrow[c] * (double)w_men[c];
      for (int off = 32; off; off >>= 1) acc += __shfl_down(acc, off);
      if (!lane) u[wg] = acc;
    }
  }
  if (blk >= 479) {
    int idx = (blk - 479) * 256 + t;
    if (idx < NW * HDIM) {
      int w = idx / HDIM, n = idx % HDIM;
      float acc = b_out[n];
      for (int d = 0; d < WDIM; ++d)
        acc += wemb[w * WDIM + d] * W_out[(size_t)(2 * HDIM + d) * HDIM + n];
      for (int c = 0; c < HDIM; ++c)
        acc += b_start[c] * W_out[(size_t)c * HDIM + n] +
               b_end[c]   * W_out[(size_t)(HDIM + c) * HDIM + n];
      W3[idx] = acc;
    }
  }
  gbar(flg, gen, 0, blk);

  // ================= P1: M1t/M2t GEMMs + vs/ve/mwc =================
  if (blk < 288) {
    bool isM2 = blk >= 144;
    int tau = isM2 ? blk - 144 : blk;
    int Mt = (tau % 12) * 64, Nt = (tau / 12) * 64;
    const float* A = isM2 ? W_end : W_start;
    int koff = isM2 ? HDIM : 0;
    unsigned short* Btx = isM2 ? Bt2 : Bt1;
    short* Al = (short*)smem;
    short* Bl = (short*)(smem + 64 * LSTR * 2);
    f32x4 acc[4];
    #pragma unroll
    for (int i = 0; i < 4; ++i) acc[i] = {0.f, 0.f, 0.f, 0.f};
    for (int kk = 0; kk < HDIM; kk += 32) {
      {
        const float* src = A + (size_t)(Mt + rs) * HDIM + kk + ch * 8;
        float4 x = *(const float4*)src, y = *(const float4*)(src + 4);
        bf16x8 pk;
        pk[0]=(short)f2b(x.x); pk[1]=(short)f2b(x.y); pk[2]=(short)f2b(x.z); pk[3]=(short)f2b(x.w);
        pk[4]=(short)f2b(y.x); pk[5]=(short)f2b(y.y); pk[6]=(short)f2b(y.z); pk[7]=(short)f2b(y.w);
        *(bf16x8*)&Al[rs * LSTR + ch * 8] = pk;
      }
      *(u16x8*)&Bl[rs * LSTR + ch * 8] =
        *(const u16x8*)(Wot + (size_t)(Nt + rs) * FPAD + koff + kk + ch * 8);
      __syncthreads();
      bf16x8 a = *(bf16x8*)&Al[(wv * 16 + coll) * LSTR + quad * 8];
      #pragma unroll
      for (int ct = 0; ct < 4; ++ct) {
        bf16x8 bfr = *(bf16x8*)&Bl[(ct * 16 + coll) * LSTR + quad * 8];
        acc[ct] = __builtin_amdgcn_mfma_f32_16x16x32_bf16(a, bfr, acc[ct], 0, 0, 0);
      }
      __syncthreads();
    }
    #pragma unroll
    for (int ct = 0; ct < 4; ++ct) {
      int n = Nt + ct * 16 + coll;
      #pragma unroll
      for (int reg = 0; reg < 4; ++reg) {
        int h = Mt + wv * 16 + quad * 4 + reg;
        Btx[(size_t)n * HDIM + h] = f2b(acc[ct][reg]);
      }
    }
  }
  {
    int wg = blk * 4 + wv;
    if (wg < 2 * HDIM) {
      if (wg < HDIM) {
        const float* Wrow = W_start + (size_t)wg * HDIM;
        double acc = 0.0;
        for (int j = lane; j < HDIM; j += 64) acc += (double)Wrow[j] * u[j];
        for (int off = 32; off; off >>= 1) acc += __shfl_down(acc, off);
        if (!lane) vs[wg] = (float)acc;
      } else {
        int r = wg - HDIM;
        const float* Wrow = W_end + (size_t)r * HDIM;
        double acc = 0.0;
        for (int j = lane; j < HDIM; j += 64) acc += (double)Wrow[j] * u[HDIM + j];
        for (int off = 32; off; off >>= 1) acc += __shfl_down(acc, off);
        if (!lane) ve[r] = (float)acc;
      }
    }
    if (wg == 0) {
      double acc = 0.0;
      for (int j = lane; j < HDIM; j += 64)
        acc += (double)b_start[j] * u[j] + (double)b_end[j] * u[HDIM + j] +
               (double)b_out[j] * (double)w_men[j];
      for (int off = 32; off; off >>= 1) acc += __shfl_down(acc, off);
      if (!lane) mwc[11] = acc + (double)b_men[0];
      if (lane < NW) {
        double a = 0.0;
        for (int d = 0; d < WDIM; ++d) a += (double)wemb[lane * WDIM + d] * u[2 * HDIM + d];
        mwc[lane] = a;
      }
    }
  }
  gbar(flg, gen, 1, blk);

  // ================= P2: token scores (exact fp64) =================
  {
    const float4* pa = (const float4*)vs;
    const float4* pb = (const float4*)ve;
    for (int q = 0; q < 16; ++q) {
      int row = blk * 64 + wv * 16 + q;
      const float4* p = (const float4*)(seq + (size_t)row * HDIM);
      double as = 0.0, ae = 0.0;
      #pragma unroll
      for (int k = 0; k < 3; ++k) {
        float4 x = p[lane + 64 * k];
        float4 a = pa[lane + 64 * k];
        float4 b = pb[lane + 64 * k];
        as += (double)x.x * a.x + (double)x.y * a.y + (double)x.z * a.z + (double)x.w * a.w;
        ae += (double)x.x * b.x + (double)x.y * b.y + (double)x.z * b.z + (double)x.w * b.w;
      }
      for (int off = 32; off; off >>= 1) { as += __shfl_down(as, off); ae += __shfl_down(ae, off); }
      if (!lane) { ms[row] = as; me[row] = ae; }
    }
  }
  gbar(flg, gen, 2, blk);

  // ================= P3: mention scores + top-50 (blocks 0..7) =================
  if (blk < BATCH) {
    int b = blk;
    unsigned (*h8)[256] = (unsigned (*)[256])smem;           // 8 KB
    unsigned* histc = (unsigned*)(smem + 8192);              // 1 KB
    int* ctrl = (int*)(smem + 9216);                         // T1,G1,T2,cnt
    float* sval = (float*)(smem + 9248);                     // 8 KB
    int*   sidx = (int*)(smem + 9248 + SURV_CAP * 4);        // 8 KB
    int hg = t >> 5;

    for (int i = t; i < 2048; i += 256) ((unsigned*)h8)[i] = 0;
    histc[t] = 0;
    if (t == 0) ctrl[3] = 0;
    double c0 = mwc[11];
    float v[32]; unsigned key[32];
    #pragma unroll
    for (int i = 0; i < 32; ++i) {
      int gi = b * NSPAN + i * 256 + t;
      int s = sp_st[gi], e = sp_en[gi];
      int w = e - s; w = w < 0 ? 0 : (w > NW - 1 ? NW - 1 : w);
      v[i] = (float)(ms[b * SDIM + s] + me[b * SDIM + e] + mwc[w] + c0);
      union { float f; unsigned u; } x; x.f = v[i];
      key[i] = (x.u >> 31) ? ~x.u : (x.u | 0x80000000u);
    }
    __syncthreads();
    #pragma unroll
    for (int i = 0; i < 32; ++i) atomicAdd(&h8[hg][key[i] >> 24], 1u);
    __syncthreads();
    { unsigned c = 0;
      #pragma unroll
      for (int g = 0; g < 8; ++g) c += h8[g][t];
      histc[t] = c; }
    __syncthreads();
    if (t < 64) {
      unsigned suf = histc[4 * lane] + histc[4 * lane + 1] + histc[4 * lane + 2] + histc[4 * lane + 3];
      #pragma unroll
      for (int off = 1; off < 64; off <<= 1) {
        unsigned o = __shfl_down(suf, off);
        if (lane + off < 64) suf += o;
      }
      unsigned long long mk = __ballot(suf >= 50u);
      int g = 63 - __builtin_clzll(mk);
      unsigned cab = __shfl(suf, g < 63 ? g + 1 : 63);
      if (g == 63) cab = 0;
      if (lane == 0) {
        unsigned cg = cab; int T1 = 4 * g;
        for (int k = 3; k >= 0; --k) {
          unsigned c = histc[4 * g + k];
          if (cg + c >= 50u) { T1 = 4 * g + k; break; }
          cg += c;
        }
        ctrl[0] = T1; ctrl[1] = (int)cg;
      }
    }
    __syncthreads();
    int T1 = ctrl[0];
    unsigned target = 50u - (unsigned)ctrl[1];
    for (int i = t; i < 2048; i += 256) ((unsigned*)h8)[i] = 0;
    __syncthreads();
    #pragma unroll
    for (int i = 0; i < 32; ++i)
      if ((int)(key[i] >> 24) == T1) atomicAdd(&h8[hg][(key[i] >> 16) & 255], 1u);
    __syncthreads();
    { unsigned c = 0;
      #pragma unroll
      for (int g = 0; g < 8; ++g) c += h8[g][t];
      histc[t] = c; }
    __syncthreads();
    if (t < 64) {
      unsigned suf = histc[4 * lane] + histc[4 * lane + 1] + histc[4 * lane + 2] + histc[4 * lane + 3];
      #pragma unroll
      for (int off = 1; off < 64; off <<= 1) {
        unsigned o = __shfl_down(suf, off);
        if (lane + off < 64) suf += o;
      }
      unsigned long long mk = __ballot(suf >= target);
      int g = 63 - __builtin_clzll(mk);
      unsigned cab = __shfl(suf, g < 63 ? g + 1 : 63);
      if (g == 63) cab = 0;
      if (lane == 0) {
        unsigned cg = cab; int T2 = 4 * g;
        for (int k = 3; k >= 0; --k) {
          unsigned c = histc[4 * g + k];
          if (cg + c >= target) { T2 = 4 * g + k; break; }
          cg += c;
        }
        ctrl[2] = T2;
      }
    }
    __syncthreads();
    unsigned thr16 = ((unsigned)T1 << 8) | (unsigned)ctrl[2];
    #pragma unroll
    for (int i = 0; i < 32; ++i) {
      if ((key[i] >> 16) >= thr16) {
        unsigned p = atomicAdd((unsigned*)&ctrl[3], 1u);
        if (p < SURV_CAP) { sval[p] = v[i]; sidx[p] = i * 256 + t; }
      }
    }
    __syncthreads();
    int n = ctrl[3] < SURV_CAP ? ctrl[3] : SURV_CAP;
    for (int m = t; m < n; m += 256) {
      float mv = sval[m]; int mi = sidx[m];
      int rank = 0;
      for (int s = 0; s < n; ++s) {
        float ov = sval[s]; int oi = sidx[s];
        rank += (ov > mv || (ov == mv && oi < mi)) ? 1 : 0;
      }
      if (rank < TK) {
        out[b * TK + rank] = mv;
        int gi = b * NSPAN + mi;
        int s0 = sp_st[gi], e0 = sp_en[gi];
        int w = e0 - s0; w = w < 0 ? 0 : (w > NW - 1 ? NW - 1 : w);
        sel_s[b * TK + rank] = s0; sel_e[b * TK + rank] = e0; sel_w[b * TK + rank] = w;
      }
    }
  }
  gbar(flg, gen, 3, blk);

  // ================= P4: repr gather-GEMM (K=1536) + Rb (blocks 0..83) =================
  if (blk < 84) {
    int Mt = (blk / 12) * 64, Nt = (blk % 12) * 64;
    short* Al = (short*)smem;
    short* Bl = (short*)(smem + 64 * LSTR * 2);
    f32x4 acc[4];
    #pragma unroll
    for (int i = 0; i < 4; ++i) acc[i] = {0.f, 0.f, 0.f, 0.f};
    int r_s = Mt + rs;
    bool okr = r_s < 400;
    int bb = okr ? r_s / TK : 0;
    const float* ps = seq + ((size_t)bb * SDIM + (okr ? sel_s[r_s] : 0)) * HDIM;
    const float* pe = seq + ((size_t)bb * SDIM + (okr ? sel_e[r_s] : 0)) * HDIM;
    for (int kk = 0; kk < 2 * HDIM; kk += 32) {
      bool ph1 = kk < HDIM;
      int kl = ph1 ? kk : kk - HDIM;
      {
        bf16x8 pk = {0, 0, 0, 0, 0, 0, 0, 0};
        if (okr) {
          const float* src = (ph1 ? ps : pe) + kl + ch * 8;
          float4 x = *(const float4*)src, y = *(const float4*)(src + 4);
          pk[0]=(short)f2b(x.x); pk[1]=(short)f2b(x.y); pk[2]=(short)f2b(x.z); pk[3]=(short)f2b(x.w);
          pk[4]=(short)f2b(y.x); pk[5]=(short)f2b(y.y); pk[6]=(short)f2b(y.z); pk[7]=(short)f2b(y.w);
        }
        *(bf16x8*)&Al[rs * LSTR + ch * 8] = pk;
      }
      *(u16x8*)&Bl[rs * LSTR + ch * 8] =
        *(const u16x8*)((ph1 ? Bt1 : Bt2) + (size_t)(Nt + rs) * HDIM + kl + ch * 8);
      __syncthreads();
      bf16x8 a = *(bf16x8*)&Al[(wv * 16 + coll) * LSTR + quad * 8];
      #pragma unroll
      for (int ct = 0; ct < 4; ++ct) {
        bf16x8 bfr = *(bf16x8*)&Bl[(ct * 16 + coll) * LSTR + quad * 8];
        acc[ct] = __builtin_amdgcn_mfma_f32_16x16x32_bf16(a, bfr, acc[ct], 0, 0, 0);
      }
      __syncthreads();
    }
    #pragma unroll
    for (int reg = 0; reg < 4; ++reg) {
      int r = Mt + wv * 16 + quad * 4 + reg;
      if (r < 400) {
        int w3r = sel_w[r];
        #pragma unroll
        for (int ct = 0; ct < 4; ++ct) {
          int c = Nt + ct * 16 + coll;
          float o = acc[ct][reg] + W3[(size_t)w3r * HDIM + c];
          Rb[(size_t)r * HDIM + c] = f2b(o);
        }
      }
    }
  }
  gbar(flg, gen, 4, blk);

  // ================= P5: Pcat GEMM (blocks 0..34) =================
  if (blk < 35) {
    int Mt = (blk / 5) * 64, Nt = (blk % 5) * 64;
    short* Al = (short*)smem;
    short* Bl = (short*)(smem + 64 * LSTR * 2);
    f32x4 acc[4];
    #pragma unroll
    for (int i = 0; i < 4; ++i) acc[i] = {0.f, 0.f, 0.f, 0.f};
    int r_s = Mt + rs;
    for (int kk = 0; kk < HDIM; kk += 32) {
      u16x8 av = {0,0,0,0,0,0,0,0};
      if (r_s < 400) av = *(const u16x8*)(Rb + (size_t)r_s * HDIM + kk + ch * 8);
      *(u16x8*)&Al[rs * LSTR + ch * 8] = av;
      *(u16x8*)&Bl[rs * LSTR + ch * 8] =
        *(const u16x8*)(Wct + (size_t)(Nt + rs) * HDIM + kk + ch * 8);
      __syncthreads();
      bf16x8 a = *(bf16x8*)&Al[(wv * 16 + coll) * LSTR + quad * 8];
      #pragma unroll
      for (int ct = 0; ct < 4; ++ct) {
        bf16x8 bfr = *(bf16x8*)&Bl[(ct * 16 + coll) * LSTR + quad * 8];
        acc[ct] = __builtin_amdgcn_mfma_f32_16x16x32_bf16(a, bfr, acc[ct], 0, 0, 0);
      }
      __syncthreads();
    }
    #pragma unroll
    for (int ct = 0; ct < 4; ++ct) {
      int c = Nt + ct * 16 + coll;
      if (c < 300) {
        #pragma unroll
        for (int reg = 0; reg < 4; ++reg) {
          int r = Mt + wv * 16 + quad * 4 + reg;
          if (r < 400) Pcat[(size_t)r * 300 + c] = acc[ct][reg];
        }
      }
    }
  }
  gbar(flg, gen, 5, blk);

  // ================= P6: pair scorer + ant fill + mask (blocks 0..319) =================
  if (blk < 320) {
    int ptile = blk % 40, b = blk / 40;
    float* ant  = out + 400;
    float* mask = out + 400 + BATCH * TK * TK;
    short* Al = (short*)smem;
    short* Bl = (short*)(smem + 64 * LSTR * 2);
    f32x4 acc[10];
    #pragma unroll
    for (int i = 0; i < 10; ++i) acc[i] = {0.f, 0.f, 0.f, 0.f};
    int pr_s = ptile * 64 + rs; if (pr_s >= 2500) pr_s = 0;
    const unsigned short* Ri = Rb + ((size_t)b * TK + pr_s / TK) * HDIM;
    const unsigned short* Rj = Rb + ((size_t)b * TK + pr_s % TK) * HDIM;

    for (int kk = 0; kk < HDIM; kk += 32) {
      {
        u16x8 ri = *(const u16x8*)(Ri + kk + ch * 8);
        u16x8 rj = *(const u16x8*)(Rj + kk + ch * 8);
        bf16x8 pk;
        #pragma unroll
        for (int q = 0; q < 8; ++q) pk[q] = (short)f2b(b2f(ri[q]) * b2f(rj[q]));
        *(bf16x8*)&Al[rs * LSTR + ch * 8] = pk;
      }
      #pragma unroll
      for (int q = 0; q < 3; ++q) {
        int idx = t + 256 * q;
        if (idx < 640) {
          int c = idx >> 2, cch = idx & 3;
          *(u16x8*)&Bl[c * LSTR + cch * 8] =
            *(const u16x8*)(Wpd + (size_t)c * HDIM + kk + cch * 8);
        }
      }
      __syncthreads();
      bf16x8 a = *(bf16x8*)&Al[(wv * 16 + coll) * LSTR + quad * 8];
      #pragma unroll
      for (int ct = 0; ct < 10; ++ct) {
        bf16x8 bfr = *(bf16x8*)&Bl[(ct * 16 + coll) * LSTR + quad * 8];
        acc[ct] = __builtin_amdgcn_mfma_f32_16x16x32_bf16(a, bfr, acc[ct], 0, 0, 0);
      }
      __syncthreads();
    }

    float gc[10], bbc[10], w2c[10], b1c[10];
    #pragma unroll
    for (int ct = 0; ct < 10; ++ct) {
      int c = ct * 16 + coll;
      bool vv2 = c < PHID;
      gc[ct] = vv2 ? ln_g[c] : 0.f; bbc[ct] = vv2 ? ln_b[c] : 0.f;
      w2c[ct] = vv2 ? W_p2[c] : 0.f; b1c[ct] = vv2 ? b_p1[c] : 0.f;
    }
    float bp2v = b_p2[0];

    #pragma unroll
    for (int reg = 0; reg < 4; ++reg) {
      int pr = ptile * 64 + wv * 16 + quad * 4 + reg;
      if (pr < 2500) {
        int i = pr / TK, j = pr % TK;
        float d = 0.f;
        if (j < i) {
          const float* Pi = Pcat + (size_t)(b * TK + i) * 300;
          const float* Pj = Pcat + (size_t)(b * TK + j) * 300 + PHID;
          float rr[10]; float sum = 0.f, sumsq = 0.f;
          #pragma unroll
          for (int ct = 0; ct < 10; ++ct) {
            int c = ct * 16 + coll;
            float v = 0.f;
            if (c < PHID) {
              v = acc[ct][reg] + Pi[c] + Pj[c] + b1c[ct];
              v = v > 0.f ? v : 0.f;
            }
            rr[ct] = v; sum += v; sumsq += v * v;
          }
          #pragma unroll
          for (int off = 1; off < 16; off <<= 1) {
            sum   += __shfl_xor(sum, off);
            sumsq += __shfl_xor(sumsq, off);
          }
          float mu  = sum * (1.f / PHID);
          float var = sumsq * (1.f / PHID) - mu * mu;
          float inv = rsqrtf(var + 1e-5f);
          #pragma unroll
          for (int ct = 0; ct < 10; ++ct)
            d += ((rr[ct] - mu) * inv * gc[ct] + bbc[ct]) * w2c[ct];
          #pragma unroll
          for (int off = 1; off < 16; off <<= 1) d += __shfl_xor(d, off);
          d += bp2v;
        }
        if (coll == 0) ant[(size_t)b * 2500 + pr] = (j < i) ? d : 0.0f;
      }
    }
    if (b == 0 && t < 64) {
      int pr = ptile * 64 + t;
      if (pr < 2500) mask[pr] = ((pr % TK) < (pr / TK)) ? 1.0f : 0.0f;
    }
  }
}

// ============================ launch ============================

extern "C" void kernel_launch(void* const* d_in, const int* in_sizes, int n_in,
                              void* d_out, int out_size, void* d_ws, size_t ws_size,
                              hipStream_t stream) {
  k_mega<<<dim3(NBLK), dim3(256), 0, stream>>>(
      (const float*)d_in[0], (const int*)d_in[1], (const int*)d_in[2],
      (const float*)d_in[3], (const float*)d_in[4], (const float*)d_in[5],
      (const float*)d_in[6], (const float*)d_in[7], (const float*)d_in[8],
      (const float*)d_in[9], (const float*)d_in[10], (const float*)d_in[11],
      (const float*)d_in[12], (const float*)d_in[13], (const float*)d_in[14],
      (const float*)d_in[15], (const float*)d_in[16], (const float*)d_in[17],
      (float*)d_out, (char*)d_ws);
}

// Round 7
// 364.890 us; speedup vs baseline: 1.4608x; 1.4608x over previous
//
#include <hip/hip_runtime.h>

#define HDIM 768
#define SDIM 4096
#define BATCH 8
#define NSPAN 8192
#define TK 50
#define WDIM 30
#define NW 11
#define PHID 150
#define FDIM 1566
#define FPAD 1568
#define LSTR 40
#define SURV_CAP 2048

typedef short  bf16x8 __attribute__((ext_vector_type(8)));
typedef unsigned short u16x8 __attribute__((ext_vector_type(8)));
typedef float  f32x4  __attribute__((ext_vector_type(4)));

__device__ __forceinline__ float b2f(unsigned short u) {
  union { unsigned int i; float f; } x; x.i = (unsigned int)u << 16; return x.f;
}
__device__ __forceinline__ unsigned short f2b(float f) {
  union { float f; unsigned int i; } x; x.f = f;
  unsigned int u = x.i;
  return (unsigned short)((u + 0x7fffu + ((u >> 16) & 1u)) >> 16);
}

// ---- shared workspace layout (all offsets 16B-aligned where vector-loaded) ----
constexpr size_t OFF_U   = 0;                                // double[1568]
constexpr size_t OFF_VS  = OFF_U   + 1568 * 8;               // float[768]
constexpr size_t OFF_VE  = OFF_VS  + 768 * 4;                // float[768]
constexpr size_t OFF_MWC = OFF_VE  + 768 * 4;                // double[16]
constexpr size_t OFF_MS  = OFF_MWC + 16 * 8;                 // double[32768]
constexpr size_t OFF_ME  = OFF_MS  + 32768 * 8;              // double[32768]
constexpr size_t OFF_SS  = OFF_ME  + 32768 * 8;              // int[512]
constexpr size_t OFF_SE  = OFF_SS  + 512 * 4;                // int[512]
constexpr size_t OFF_SW  = OFF_SE  + 512 * 4;                // int[512]
constexpr size_t OFF_W3  = OFF_SW  + 512 * 4;                // float[11*768]
constexpr size_t OFF_W3C = OFF_W3  + 11 * 768 * 4;           // float[11*300]
constexpr size_t OFF_WOT = OFF_W3C + 11 * 300 * 4;           // u16[768*1568]
constexpr size_t OFF_WCT = OFF_WOT + (size_t)768 * FPAD * 2; // u16[320*768]
constexpr size_t OFF_WPD = OFF_WCT + (size_t)320 * 768 * 2;  // u16[160*768]
constexpr size_t OFF_M1  = OFF_WPD + (size_t)160 * 768 * 2;  // u16[768*768]  (M1 [h][c])
constexpr size_t OFF_M2  = OFF_M1  + (size_t)768 * 768 * 2;  // u16[768*768]
constexpr size_t OFF_BC  = OFF_M2  + (size_t)768 * 768 * 2;  // u16[1088*1536] (B^T: rows<768 Rb-cols, 768..1067 Pcat-cols)
constexpr size_t OFF_RB  = OFF_BC  + (size_t)1088 * 1536 * 2;// u16[400*768]
constexpr size_t OFF_PC  = OFF_RB  + (size_t)400 * 768 * 2;  // f32[400*300]

// ================= K1: weight prep (Wot, Wct, Wpd, u, W3) =================
__global__ __launch_bounds__(256) void k_prep(
    const float* __restrict__ W_start, const float* __restrict__ b_start,
    const float* __restrict__ W_end, const float* __restrict__ b_end,
    const float* __restrict__ wemb, const float* __restrict__ W_out,
    const float* __restrict__ b_out, const float* __restrict__ w_men,
    const float* __restrict__ W_p1, char* __restrict__ ws) {
  unsigned short* Wot = (unsigned short*)(ws + OFF_WOT);
  unsigned short* Wct = (unsigned short*)(ws + OFF_WCT);
  unsigned short* Wpd = (unsigned short*)(ws + OFF_WPD);
  double* u  = (double*)(ws + OFF_U);
  float*  W3 = (float*)(ws + OFF_W3);
  int blk = blockIdx.x, t = threadIdx.x;
  int wv = t >> 6, lane = t & 63;
  __shared__ float Tl[32][33];
  int rr = t >> 5, cc = t & 31;
  // W_out transpose -> Wot [768][1568] bf16
  for (int j = blk; j < 49 * 24; j += 512) {
    int k0 = (j % 49) * 32, n0 = (j / 49) * 32;
    #pragma unroll
    for (int q = 0; q < 4; ++q) {
      int kr = rr + q * 8, kk = k0 + kr;
      Tl[kr][cc] = (kk < FDIM) ? W_out[(size_t)kk * HDIM + n0 + cc] : 0.f;
    }
    __syncthreads();
    #pragma unroll
    for (int q = 0; q < 4; ++q) {
      int nr = rr + q * 8;
      Wot[(size_t)(n0 + nr) * FPAD + k0 + cc] = f2b(Tl[cc][nr]);
    }
    __syncthreads();
  }
  // Wct [320][768], Wpd [160][768]
  for (int idx = blk * 256 + t; idx < 480 * HDIM; idx += 512 * 256) {
    if (idx < 320 * HDIM) {
      int n = idx / HDIM, h = idx % HDIM;
      float v = 0.f;
      if (n < PHID)      v = W_p1[(size_t)h * PHID + n] + W_p1[(size_t)(2 * HDIM + h) * PHID + n];
      else if (n < 300)  v = W_p1[(size_t)(HDIM + h) * PHID + (n - PHID)] -
                             W_p1[(size_t)(2 * HDIM + h) * PHID + (n - PHID)];
      Wct[idx] = f2b(v);
    } else {
      int j = idx - 320 * HDIM;
      int n = j / HDIM, h = j % HDIM;
      Wpd[j] = f2b((n < PHID) ? W_p1[(size_t)(3 * HDIM + h) * PHID + n] : 0.f);
    }
  }
  // u = W_out @ w_men (fp64 exact)
  {
    int wg = blk * 4 + wv;
    if (wg < FDIM) {
      const float* Wrow = W_out + (size_t)wg * HDIM;
      double acc = 0.0;
      for (int c = lane; c < HDIM; c += 64) acc += (double)Wrow[c] * (double)w_men[c];
      for (int off = 32; off; off >>= 1) acc += __shfl_down(acc, off);
      if (!lane) u[wg] = acc;
    }
  }
  // W3[w][n] = b_out + wemb[w]@W_out_wid + b_start@W_out_top + b_end@W_out_mid
  if (blk >= 479) {
    int idx = (blk - 479) * 256 + t;
    if (idx < NW * HDIM) {
      int w = idx / HDIM, n = idx % HDIM;
      float acc = b_out[n];
      for (int d = 0; d < WDIM; ++d)
        acc += wemb[w * WDIM + d] * W_out[(size_t)(2 * HDIM + d) * HDIM + n];
      for (int c = 0; c < HDIM; ++c)
        acc += b_start[c] * W_out[(size_t)c * HDIM + n] +
               b_end[c]   * W_out[(size_t)(HDIM + c) * HDIM + n];
      W3[idx] = acc;
    }
  }
}

// ================= K2: M1/M2 GEMMs + vs/ve/mwc + W3C =================
__global__ __launch_bounds__(256) void k_mid(
    const float* __restrict__ W_start, const float* __restrict__ W_end,
    const float* __restrict__ b_start, const float* __restrict__ b_end,
    const float* __restrict__ b_out, const float* __restrict__ w_men,
    const float* __restrict__ b_men, const float* __restrict__ wemb,
    char* __restrict__ ws) {
  unsigned short* Wot = (unsigned short*)(ws + OFF_WOT);
  unsigned short* Wct = (unsigned short*)(ws + OFF_WCT);
  unsigned short* M1  = (unsigned short*)(ws + OFF_M1);
  unsigned short* M2  = (unsigned short*)(ws + OFF_M2);
  unsigned short* Bc  = (unsigned short*)(ws + OFF_BC);
  double* u   = (double*)(ws + OFF_U);
  float*  vs  = (float*)(ws + OFF_VS);
  float*  ve  = (float*)(ws + OFF_VE);
  double* mwc = (double*)(ws + OFF_MWC);
  float*  W3  = (float*)(ws + OFF_W3);
  float*  W3C = (float*)(ws + OFF_W3C);
  int blk = blockIdx.x, t = threadIdx.x;
  int wv = t >> 6, lane = t & 63, quad = lane >> 4, coll = lane & 15;
  int rs = t >> 2, ch = t & 3;
  __shared__ short Al[64 * LSTR];
  __shared__ short Bl[64 * LSTR];

  if (blk < 288) {
    // M1 = W_start @ W_out_top ; M2 = W_end @ W_out_mid   (bf16 MFMA, pipelined)
    bool isM2 = blk >= 144;
    int tau = isM2 ? blk - 144 : blk;
    int Mt = (tau % 12) * 64, Nt = (tau / 12) * 64;
    const float* A = isM2 ? W_end : W_start;
    int koff = isM2 ? HDIM : 0;
    unsigned short* Mnt = isM2 ? M2 : M1;
    const float* asrc = A + (size_t)(Mt + rs) * HDIM + ch * 8;
    const unsigned short* bsrc = Wot + (size_t)(Nt + rs) * FPAD + koff + ch * 8;
    f32x4 acc[4];
    #pragma unroll
    for (int i = 0; i < 4; ++i) acc[i] = {0.f, 0.f, 0.f, 0.f};
    float4 ax = *(const float4*)asrc, ay = *(const float4*)(asrc + 4);
    u16x8 bx = *(const u16x8*)bsrc;
    for (int it = 0; it < 24; ++it) {
      bf16x8 pk;
      pk[0]=(short)f2b(ax.x); pk[1]=(short)f2b(ax.y); pk[2]=(short)f2b(ax.z); pk[3]=(short)f2b(ax.w);
      pk[4]=(short)f2b(ay.x); pk[5]=(short)f2b(ay.y); pk[6]=(short)f2b(ay.z); pk[7]=(short)f2b(ay.w);
      *(bf16x8*)&Al[rs * LSTR + ch * 8] = pk;
      *(u16x8*)&Bl[rs * LSTR + ch * 8] = bx;
      __syncthreads();
      if (it < 23) {
        ax = *(const float4*)(asrc + (it + 1) * 32);
        ay = *(const float4*)(asrc + (it + 1) * 32 + 4);
        bx = *(const u16x8*)(bsrc + (it + 1) * 32);
      }
      bf16x8 a = *(bf16x8*)&Al[(wv * 16 + coll) * LSTR + quad * 8];
      #pragma unroll
      for (int ct = 0; ct < 4; ++ct) {
        bf16x8 bfr = *(bf16x8*)&Bl[(ct * 16 + coll) * LSTR + quad * 8];
        acc[ct] = __builtin_amdgcn_mfma_f32_16x16x32_bf16(a, bfr, acc[ct], 0, 0, 0);
      }
      __syncthreads();
    }
    #pragma unroll
    for (int ct = 0; ct < 4; ++ct) {
      int n = Nt + ct * 16 + coll;
      #pragma unroll
      for (int reg = 0; reg < 4; ++reg) {
        int h = Mt + wv * 16 + quad * 4 + reg;
        unsigned short v = f2b(acc[ct][reg]);
        Bc[(size_t)n * 1536 + koff + h] = v;   // transposed for K5's B operand
        Mnt[(size_t)h * HDIM + n] = v;         // row-major for K3's chain GEMM
      }
    }
  } else if (blk < 673) {
    // vs/ve/mwc (fp64 exact)
    int wg = (blk - 288) * 4 + wv;
    if (wg < HDIM) {
      const float* Wrow = W_start + (size_t)wg * HDIM;
      double acc = 0.0;
      for (int j = lane; j < HDIM; j += 64) acc += (double)Wrow[j] * u[j];
      for (int off = 32; off; off >>= 1) acc += __shfl_down(acc, off);
      if (!lane) vs[wg] = (float)acc;
    } else if (wg < 2 * HDIM) {
      int r = wg - HDIM;
      const float* Wrow = W_end + (size_t)r * HDIM;
      double acc = 0.0;
      for (int j = lane; j < HDIM; j += 64) acc += (double)Wrow[j] * u[HDIM + j];
      for (int off = 32; off; off >>= 1) acc += __shfl_down(acc, off);
      if (!lane) ve[r] = (float)acc;
    } else if (wg == 2 * HDIM) {
      double acc = 0.0;
      for (int j = lane; j < HDIM; j += 64)
        acc += (double)b_start[j] * u[j] + (double)b_end[j] * u[HDIM + j] +
               (double)b_out[j] * (double)w_men[j];
      for (int off = 32; off; off >>= 1) acc += __shfl_down(acc, off);
      if (!lane) mwc[11] = acc + (double)b_men[0];
      if (lane < NW) {
        double a = 0.0;
        for (int d = 0; d < WDIM; ++d) a += (double)wemb[lane * WDIM + d] * u[2 * HDIM + d];
        mwc[lane] = a;
      }
    }
  } else {
    // W3C[w][p] = sum_c W3[w][c] * Wct[p][c]
    int oid = (blk - 673) * 4 + wv;
    if (oid < NW * 300) {
      int w = oid / 300, p = oid % 300;
      const float* w3r = W3 + (size_t)w * HDIM;
      const unsigned short* wcr = Wct + (size_t)p * HDIM;
      float acc = 0.f;
      for (int c = lane; c < HDIM; c += 64) acc += w3r[c] * b2f(wcr[c]);
      for (int off = 32; off; off >>= 1) acc += __shfl_down(acc, off);
      if (!lane) W3C[w * 300 + p] = acc;
    }
  }
}

// ================= K3: token scores (fp64 exact) + M1C/M2C chain GEMMs =================
__global__ __launch_bounds__(256) void k_tok(const float* __restrict__ seq,
                                             char* __restrict__ ws) {
  double* ms = (double*)(ws + OFF_MS);
  double* me = (double*)(ws + OFF_ME);
  const float* vs = (const float*)(ws + OFF_VS);
  const float* ve = (const float*)(ws + OFF_VE);
  unsigned short* Wct = (unsigned short*)(ws + OFF_WCT);
  unsigned short* M1  = (unsigned short*)(ws + OFF_M1);
  unsigned short* M2  = (unsigned short*)(ws + OFF_M2);
  unsigned short* Bc  = (unsigned short*)(ws + OFF_BC);
  int blk = blockIdx.x, t = threadIdx.x;
  int wv = t >> 6, lane = t & 63, quad = lane >> 4, coll = lane & 15;
  int rs = t >> 2, ch = t & 3;
  __shared__ short Al[64 * LSTR];
  __shared__ short Bl[64 * LSTR];

  if (blk < 8192) {
    int row = blk * 4 + wv;
    const float4* p  = (const float4*)(seq + (size_t)row * HDIM);
    const float4* pa = (const float4*)vs;
    const float4* pb = (const float4*)ve;
    double as = 0.0, ae = 0.0;
    #pragma unroll
    for (int k = 0; k < 3; ++k) {
      float4 x = p[lane + 64 * k];
      float4 a = pa[lane + 64 * k];
      float4 b = pb[lane + 64 * k];
      as += (double)x.x * a.x + (double)x.y * a.y + (double)x.z * a.z + (double)x.w * a.w;
      ae += (double)x.x * b.x + (double)x.y * b.y + (double)x.z * b.z + (double)x.w * b.w;
    }
    for (int off = 32; off; off >>= 1) { as += __shfl_down(as, off); ae += __shfl_down(ae, off); }
    if (!lane) { ms[row] = as; me[row] = ae; }
  } else {
    // M1C^T / M2C^T: out[p][h] = sum_c Wct[p][c] * M[h][c]  -> Bc rows 768+p
    int cb = blk - 8192;
    bool isM2C = cb >= 60;
    int tau = isM2C ? cb - 60 : cb;
    int Mt = (tau / 12) * 64, Nt = (tau % 12) * 64;
    const unsigned short* Mnt = isM2C ? M2 : M1;
    int koff = isM2C ? HDIM : 0;
    const unsigned short* asrc = Wct + (size_t)(Mt + rs) * HDIM + ch * 8;
    const unsigned short* bsrc = Mnt + (size_t)(Nt + rs) * HDIM + ch * 8;
    f32x4 acc[4];
    #pragma unroll
    for (int i = 0; i < 4; ++i) acc[i] = {0.f, 0.f, 0.f, 0.f};
    u16x8 axv = *(const u16x8*)asrc;
    u16x8 bxv = *(const u16x8*)bsrc;
    for (int it = 0; it < 24; ++it) {
      *(u16x8*)&Al[rs * LSTR + ch * 8] = axv;
      *(u16x8*)&Bl[rs * LSTR + ch * 8] = bxv;
      __syncthreads();
      if (it < 23) {
        axv = *(const u16x8*)(asrc + (it + 1) * 32);
        bxv = *(const u16x8*)(bsrc + (it + 1) * 32);
      }
      bf16x8 a = *(bf16x8*)&Al[(wv * 16 + coll) * LSTR + quad * 8];
      #pragma unroll
      for (int ct = 0; ct < 4; ++ct) {
        bf16x8 bfr = *(bf16x8*)&Bl[(ct * 16 + coll) * LSTR + quad * 8];
        acc[ct] = __builtin_amdgcn_mfma_f32_16x16x32_bf16(a, bfr, acc[ct], 0, 0, 0);
      }
      __syncthreads();
    }
    #pragma unroll
    for (int ct = 0; ct < 4; ++ct) {
      int h = Nt + ct * 16 + coll;
      #pragma unroll
      for (int reg = 0; reg < 4; ++reg) {
        int p = Mt + wv * 16 + quad * 4 + reg;
        Bc[(size_t)(768 + p) * 1536 + koff + h] = f2b(acc[ct][reg]);
      }
    }
  }
}

// ================= K4: mention scores + top-50 (radix select, exact tie-break) =================
__global__ __launch_bounds__(1024) void k_topk(
    const int* __restrict__ st, const int* __restrict__ en, char* __restrict__ ws,
    float* __restrict__ out_top) {
  const double* ms  = (const double*)(ws + OFF_MS);
  const double* me  = (const double*)(ws + OFF_ME);
  const double* mwc = (const double*)(ws + OFF_MWC);
  int* sel_s = (int*)(ws + OFF_SS);
  int* sel_e = (int*)(ws + OFF_SE);
  int* sel_w = (int*)(ws + OFF_SW);
  int b = blockIdx.x, t = threadIdx.x;
  int wave = t >> 6, lane = t & 63;
  __shared__ unsigned hist[16][256];
  __shared__ unsigned histc[256], hist2[256];
  __shared__ int s_T1, s_G1, s_T2;
  __shared__ unsigned s_cnt;
  __shared__ float sval[SURV_CAP];
  __shared__ int   sidx[SURV_CAP];

  for (int i = t; i < 16 * 256; i += 1024) ((unsigned*)hist)[i] = 0;
  if (t < 256) { histc[t] = 0; hist2[t] = 0; }
  if (t == 0) s_cnt = 0;
  double c0 = mwc[11];
  float v[8]; unsigned key[8];
  #pragma unroll
  for (int i = 0; i < 8; ++i) {
    int gi = b * NSPAN + i * 1024 + t;
    int s = st[gi], e = en[gi];
    int w = e - s; w = w < 0 ? 0 : (w > NW - 1 ? NW - 1 : w);
    v[i] = (float)(ms[b * SDIM + s] + me[b * SDIM + e] + mwc[w] + c0);
    union { float f; unsigned u; } x; x.f = v[i];
    key[i] = (x.u >> 31) ? ~x.u : (x.u | 0x80000000u);
  }
  __syncthreads();
  #pragma unroll
  for (int i = 0; i < 8; ++i) atomicAdd(&hist[wave][key[i] >> 24], 1u);
  __syncthreads();
  if (t < 256) {
    unsigned c = 0;
    #pragma unroll
    for (int g = 0; g < 16; ++g) c += hist[g][t];
    histc[t] = c;
  }
  __syncthreads();
  if (t < 64) {
    unsigned suf = histc[4 * lane] + histc[4 * lane + 1] + histc[4 * lane + 2] + histc[4 * lane + 3];
    #pragma unroll
    for (int off = 1; off < 64; off <<= 1) {
      unsigned o = __shfl_down(suf, off);
      if (lane + off < 64) suf += o;
    }
    unsigned long long mk = __ballot(suf >= 50u);
    int g = 63 - __builtin_clzll(mk);
    unsigned cab = __shfl(suf, g < 63 ? g + 1 : 63);
    if (g == 63) cab = 0;
    if (lane == 0) {
      unsigned cg = cab; int T1 = 4 * g;
      for (int k = 3; k >= 0; --k) {
        unsigned c = histc[4 * g + k];
        if (cg + c >= 50u) { T1 = 4 * g + k; break; }
        cg += c;
      }
      s_T1 = T1; s_G1 = (int)cg;
    }
  }
  __syncthreads();
  int T1 = s_T1;
  unsigned target = 50u - (unsigned)s_G1;
  #pragma unroll
  for (int i = 0; i < 8; ++i)
    if ((int)(key[i] >> 24) == T1) atomicAdd(&hist2[(key[i] >> 16) & 255], 1u);
  __syncthreads();
  if (t < 64) {
    unsigned suf = hist2[4 * lane] + hist2[4 * lane + 1] + hist2[4 * lane + 2] + hist2[4 * lane + 3];
    #pragma unroll
    for (int off = 1; off < 64; off <<= 1) {
      unsigned o = __shfl_down(suf, off);
      if (lane + off < 64) suf += o;
    }
    unsigned long long mk = __ballot(suf >= target);
    int g = 63 - __builtin_clzll(mk);
    unsigned cab = __shfl(suf, g < 63 ? g + 1 : 63);
    if (g == 63) cab = 0;
    if (lane == 0) {
      unsigned cg = cab; int T2 = 4 * g;
      for (int k = 3; k >= 0; --k) {
        unsigned c = hist2[4 * g + k];
        if (cg + c >= target) { T2 = 4 * g + k; break; }
        cg += c;
      }
      s_T2 = T2;
    }
  }
  __syncthreads();
  unsigned thr16 = ((unsigned)T1 << 8) | (unsigned)s_T2;
  #pragma unroll
  for (int i = 0; i < 8; ++i) {
    if ((key[i] >> 16) >= thr16) {
      unsigned p = atomicAdd(&s_cnt, 1u);
      if (p < SURV_CAP) { sval[p] = v[i]; sidx[p] = i * 1024 + t; }
    }
  }
  __syncthreads();
  int n = s_cnt < SURV_CAP ? (int)s_cnt : SURV_CAP;
  for (int m = t; m < n; m += 1024) {
    float mv = sval[m]; int mi = sidx[m];
    int rank = 0;
    for (int s = 0; s < n; ++s) {
      float ov = sval[s]; int oi = sidx[s];
      rank += (ov > mv || (ov == mv && oi < mi)) ? 1 : 0;
    }
    if (rank < TK) {
      out_top[b * TK + rank] = mv;
      int gi = b * NSPAN + mi;
      int s0 = st[gi], e0 = en[gi];
      int w = e0 - s0; w = w < 0 ? 0 : (w > NW - 1 ? NW - 1 : w);
      sel_s[b * TK + rank] = s0; sel_e[b * TK + rank] = e0; sel_w[b * TK + rank] = w;
    }
  }
}

// ================= K5: fused span gather-GEMM (K=1536, N=1088 = Rb(768) + Pcat(300)) ===========
__global__ __launch_bounds__(256) void k_span(const float* __restrict__ seq,
                                              char* __restrict__ ws) {
  const int* sel_s = (const int*)(ws + OFF_SS);
  const int* sel_e = (const int*)(ws + OFF_SE);
  const int* sel_w = (const int*)(ws + OFF_SW);
  const float* W3  = (const float*)(ws + OFF_W3);
  const float* W3C = (const float*)(ws + OFF_W3C);
  unsigned short* Bc = (unsigned short*)(ws + OFF_BC);
  unsigned short* Rb = (unsigned short*)(ws + OFF_RB);
  float* Pcat = (float*)(ws + OFF_PC);
  int blk = blockIdx.x, t = threadIdx.x;
  int wv = t >> 6, lane = t & 63, quad = lane >> 4, coll = lane & 15;
  int rs = t >> 2, ch = t & 3;
  __shared__ short Al[64 * LSTR];
  __shared__ short Bl[64 * LSTR];

  int Mt = (blk / 17) * 64, Nt = (blk % 17) * 64;
  int r0 = Mt + rs;
  int rr2 = r0 < 400 ? r0 : 0;
  int bb = rr2 / TK;
  const float* ps = seq + ((size_t)bb * SDIM + sel_s[rr2]) * HDIM;
  const float* pe = seq + ((size_t)bb * SDIM + sel_e[rr2]) * HDIM;
  const unsigned short* bsrc = Bc + (size_t)(Nt + rs) * 1536 + ch * 8;
  f32x4 acc[4];
  #pragma unroll
  for (int i = 0; i < 4; ++i) acc[i] = {0.f, 0.f, 0.f, 0.f};
  int kg0 = ch * 8;
  const float* s0p = (kg0 < HDIM ? ps : pe) + (kg0 & (HDIM - 1));
  float4 ax = *(const float4*)s0p, ay = *(const float4*)(s0p + 4);
  u16x8 bx = *(const u16x8*)bsrc;
  for (int it = 0; it < 48; ++it) {
    bf16x8 pk;
    pk[0]=(short)f2b(ax.x); pk[1]=(short)f2b(ax.y); pk[2]=(short)f2b(ax.z); pk[3]=(short)f2b(ax.w);
    pk[4]=(short)f2b(ay.x); pk[5]=(short)f2b(ay.y); pk[6]=(short)f2b(ay.z); pk[7]=(short)f2b(ay.w);
    *(bf16x8*)&Al[rs * LSTR + ch * 8] = pk;
    *(u16x8*)&Bl[rs * LSTR + ch * 8] = bx;
    __syncthreads();
    if (it < 47) {
      int kg = (it + 1) * 32 + ch * 8;
      const float* sp = (kg < HDIM ? ps : pe) + (kg & (HDIM - 1));
      ax = *(const float4*)sp; ay = *(const float4*)(sp + 4);
      bx = *(const u16x8*)(bsrc + (it + 1) * 32);
    }
    bf16x8 a = *(bf16x8*)&Al[(wv * 16 + coll) * LSTR + quad * 8];
    #pragma unroll
    for (int ct = 0; ct < 4; ++ct) {
      bf16x8 bfr = *(bf16x8*)&Bl[(ct * 16 + coll) * LSTR + quad * 8];
      acc[ct] = __builtin_amdgcn_mfma_f32_16x16x32_bf16(a, bfr, acc[ct], 0, 0, 0);
    }
    __syncthreads();
  }
  #pragma unroll
  for (int reg = 0; reg < 4; ++reg) {
    int r = Mt + wv * 16 + quad * 4 + reg;
    if (r < 400) {
      int w = sel_w[r];
      #pragma unroll
      for (int ct = 0; ct < 4; ++ct) {
        int c = Nt + ct * 16 + coll;
        if (c < HDIM) {
          Rb[(size_t)r * HDIM + c] = f2b(acc[ct][reg] + W3[(size_t)w * HDIM + c]);
        } else if (c < HDIM + 300) {
          int p = c - HDIM;
          Pcat[(size_t)r * 300 + p] = acc[ct][reg] + W3C[w * 300 + p];
        }
      }
    }
  }
}

// ================= K6: pair scorer + ant fill + mask =================
__global__ __launch_bounds__(256) void k_pair(
    const float* __restrict__ bp1, const float* __restrict__ g,
    const float* __restrict__ bb_, const float* __restrict__ wp2,
    const float* __restrict__ bp2, float* __restrict__ out, char* __restrict__ ws) {
  const unsigned short* Rb  = (const unsigned short*)(ws + OFF_RB);
  const unsigned short* Wpd = (const unsigned short*)(ws + OFF_WPD);
  const float* Pcat = (const float*)(ws + OFF_PC);
  int blk = blockIdx.x, t = threadIdx.x;
  int ptile = blk % 40, b = blk / 40;
  int wv = t >> 6, lane = t & 63, quad = lane >> 4, coll = lane & 15;
  int rs = t >> 2, ch = t & 3;
  float* ant  = out + 400;
  float* mask = out + 400 + BATCH * TK * TK;
  __shared__ short Al[64 * LSTR];
  __shared__ short Bl[160 * LSTR];
  f32x4 acc[10];
  #pragma unroll
  for (int i = 0; i < 10; ++i) acc[i] = {0.f, 0.f, 0.f, 0.f};

  int pr_s = ptile * 64 + rs; if (pr_s >= 2500) pr_s = 0;
  const unsigned short* Ri = Rb + ((size_t)b * TK + pr_s / TK) * HDIM;
  const unsigned short* Rj = Rb + ((size_t)b * TK + pr_s % TK) * HDIM;
  int bi0 = t, bi1 = t + 256, bi2 = t + 512;   // B chunk ids (<640 valid)
  u16x8 ri = *(const u16x8*)(Ri + ch * 8);
  u16x8 rj = *(const u16x8*)(Rj + ch * 8);
  u16x8 bw0, bw1, bw2;
  bw0 = *(const u16x8*)(Wpd + (size_t)(bi0 >> 2) * HDIM + (bi0 & 3) * 8);
  bw1 = *(const u16x8*)(Wpd + (size_t)(bi1 >> 2) * HDIM + (bi1 & 3) * 8);
  if (bi2 < 640) bw2 = *(const u16x8*)(Wpd + (size_t)(bi2 >> 2) * HDIM + (bi2 & 3) * 8);

  for (int it = 0; it < 24; ++it) {
    {
      bf16x8 pk;
      #pragma unroll
      for (int q = 0; q < 8; ++q) pk[q] = (short)f2b(b2f(ri[q]) * b2f(rj[q]));
      *(bf16x8*)&Al[rs * LSTR + ch * 8] = pk;
    }
    *(u16x8*)&Bl[(bi0 >> 2) * LSTR + (bi0 & 3) * 8] = bw0;
    *(u16x8*)&Bl[(bi1 >> 2) * LSTR + (bi1 & 3) * 8] = bw1;
    if (bi2 < 640) *(u16x8*)&Bl[(bi2 >> 2) * LSTR + (bi2 & 3) * 8] = bw2;
    __syncthreads();
    if (it < 23) {
      int kk = (it + 1) * 32;
      ri = *(const u16x8*)(Ri + kk + ch * 8);
      rj = *(const u16x8*)(Rj + kk + ch * 8);
      bw0 = *(const u16x8*)(Wpd + (size_t)(bi0 >> 2) * HDIM + kk + (bi0 & 3) * 8);
      bw1 = *(const u16x8*)(Wpd + (size_t)(bi1 >> 2) * HDIM + kk + (bi1 & 3) * 8);
      if (bi2 < 640) bw2 = *(const u16x8*)(Wpd + (size_t)(bi2 >> 2) * HDIM + kk + (bi2 & 3) * 8);
    }
    bf16x8 a = *(bf16x8*)&Al[(wv * 16 + coll) * LSTR + quad * 8];
    #pragma unroll
    for (int ct = 0; ct < 10; ++ct) {
      bf16x8 bfr = *(bf16x8*)&Bl[(ct * 16 + coll) * LSTR + quad * 8];
      acc[ct] = __builtin_amdgcn_mfma_f32_16x16x32_bf16(a, bfr, acc[ct], 0, 0, 0);
    }
    __syncthreads();
  }

  float gc[10], bbc[10], w2c[10], b1c[10];
  #pragma unroll
  for (int ct = 0; ct < 10; ++ct) {
    int c = ct * 16 + coll;
    bool vv2 = c < PHID;
    gc[ct] = vv2 ? g[c] : 0.f; bbc[ct] = vv2 ? bb_[c] : 0.f;
    w2c[ct] = vv2 ? wp2[c] : 0.f; b1c[ct] = vv2 ? bp1[c] : 0.f;
  }
  float bp2v = bp2[0];

  #pragma unroll
  for (int reg = 0; reg < 4; ++reg) {
    int pr = ptile * 64 + wv * 16 + quad * 4 + reg;
    if (pr < 2500) {
      int i = pr / TK, j = pr % TK;
      float d = 0.f;
      if (j < i) {
        const float* Pi = Pcat + (size_t)(b * TK + i) * 300;
        const float* Pj = Pcat + (size_t)(b * TK + j) * 300 + PHID;
        float rr[10]; float sum = 0.f, sumsq = 0.f;
        #pragma unroll
        for (int ct = 0; ct < 10; ++ct) {
          int c = ct * 16 + coll;
          float v = 0.f;
          if (c < PHID) {
            v = acc[ct][reg] + Pi[c] + Pj[c] + b1c[ct];
            v = v > 0.f ? v : 0.f;
          }
          rr[ct] = v; sum += v; sumsq += v * v;
        }
        #pragma unroll
        for (int off = 1; off < 16; off <<= 1) {
          sum   += __shfl_xor(sum, off);
          sumsq += __shfl_xor(sumsq, off);
        }
        float mu  = sum * (1.f / PHID);
        float var = sumsq * (1.f / PHID) - mu * mu;
        float inv = rsqrtf(var + 1e-5f);
        #pragma unroll
        for (int ct = 0; ct < 10; ++ct)
          d += ((rr[ct] - mu) * inv * gc[ct] + bbc[ct]) * w2c[ct];
        #pragma unroll
        for (int off = 1; off < 16; off <<= 1) d += __shfl_xor(d, off);
        d += bp2v;
      }
      if (coll == 0) ant[(size_t)b * 2500 + pr] = (j < i) ? d : 0.0f;
    }
  }
  if (b == 0 && t < 64) {
    int pr = ptile * 64 + t;
    if (pr < 2500) mask[pr] = ((pr % TK) < (pr / TK)) ? 1.0f : 0.0f;
  }
}

// ============================ launch ============================

extern "C" void kernel_launch(void* const* d_in, const int* in_sizes, int n_in,
                              void* d_out, int out_size, void* d_ws, size_t ws_size,
                              hipStream_t stream) {
  const float* seq     = (const float*)d_in[0];
  const int*   sp_st   = (const int*)d_in[1];
  const int*   sp_en   = (const int*)d_in[2];
  const float* W_start = (const float*)d_in[3];
  const float* b_start = (const float*)d_in[4];
  const float* W_end   = (const float*)d_in[5];
  const float* b_end   = (const float*)d_in[6];
  const float* wemb    = (const float*)d_in[7];
  const float* W_out   = (const float*)d_in[8];
  const float* b_out   = (const float*)d_in[9];
  const float* w_men   = (const float*)d_in[10];
  const float* b_men   = (const float*)d_in[11];
  const float* W_p1    = (const float*)d_in[12];
  const float* b_p1    = (const float*)d_in[13];
  const float* ln_g    = (const float*)d_in[14];
  const float* ln_b    = (const float*)d_in[15];
  const float* W_p2    = (const float*)d_in[16];
  const float* b_p2    = (const float*)d_in[17];
  char* ws = (char*)d_ws;
  float* out = (float*)d_out;

  k_prep<<<dim3(512), dim3(256), 0, stream>>>(W_start, b_start, W_end, b_end, wemb,
                                              W_out, b_out, w_men, W_p1, ws);
  k_mid<<<dim3(1498), dim3(256), 0, stream>>>(W_start, W_end, b_start, b_end,
                                              b_out, w_men, b_men, wemb, ws);
  k_tok<<<dim3(8312), dim3(256), 0, stream>>>(seq, ws);
  k_topk<<<dim3(BATCH), dim3(1024), 0, stream>>>(sp_st, sp_en, ws, out);
  k_span<<<dim3(119), dim3(256), 0, stream>>>(seq, ws);
  k_pair<<<dim3(320), dim3(256), 0, stream>>>(b_p1, ln_g, ln_b, W_p2, b_p2, out, ws);
}

// Round 8
// 297.735 us; speedup vs baseline: 1.7903x; 1.2256x over previous
//
#include <hip/hip_runtime.h>

#define HDIM 768
#define SDIM 4096
#define BATCH 8
#define NSPAN 8192
#define TK 50
#define WDIM 30
#define NW 11
#define PHID 150
#define FDIM 1566
#define FPAD 1568
#define LSTR 40
#define SURV_CAP 2048

typedef short  bf16x8 __attribute__((ext_vector_type(8)));
typedef unsigned short u16x8 __attribute__((ext_vector_type(8)));
typedef float  f32x4  __attribute__((ext_vector_type(4)));

__device__ __forceinline__ float b2f(unsigned short u) {
  union { unsigned int i; float f; } x; x.i = (unsigned int)u << 16; return x.f;
}
__device__ __forceinline__ unsigned short f2b(float f) {
  union { float f; unsigned int i; } x; x.f = f;
  unsigned int u = x.i;
  return (unsigned short)((u + 0x7fffu + ((u >> 16) & 1u)) >> 16);
}

// ---- shared workspace layout ----
constexpr size_t OFF_U   = 0;                                // double[1568]
constexpr size_t OFF_VS  = OFF_U   + 1568 * 8;               // float[768]
constexpr size_t OFF_VE  = OFF_VS  + 768 * 4;                // float[768]
constexpr size_t OFF_MWC = OFF_VE  + 768 * 4;                // double[16]
constexpr size_t OFF_MS  = OFF_MWC + 16 * 8;                 // double[32768]
constexpr size_t OFF_ME  = OFF_MS  + 32768 * 8;              // double[32768]
constexpr size_t OFF_SS  = OFF_ME  + 32768 * 8;              // int[512]
constexpr size_t OFF_SE  = OFF_SS  + 512 * 4;                // int[512]
constexpr size_t OFF_SW  = OFF_SE  + 512 * 4;                // int[512]
constexpr size_t OFF_W3  = OFF_SW  + 512 * 4;                // float[11*768]  (W3partial: b_out + wemb part)
constexpr size_t OFF_W3C = OFF_W3  + 11 * 768 * 4;           // float[11*300]  (W3C': without bs3 part)
constexpr size_t OFF_WOT = OFF_W3C + 11 * 300 * 4;           // u16[768*1568]
constexpr size_t OFF_WCT = OFF_WOT + (size_t)768 * FPAD * 2; // u16[320*768]
constexpr size_t OFF_WPD = OFF_WCT + (size_t)320 * 768 * 2;  // u16[160*768]
constexpr size_t OFF_M1  = OFF_WPD + (size_t)160 * 768 * 2;  // u16[768*768]
constexpr size_t OFF_M2  = OFF_M1  + (size_t)768 * 768 * 2;  // u16[768*768]
constexpr size_t OFF_BC  = OFF_M2  + (size_t)768 * 768 * 2;  // u16[1088*1536]
constexpr size_t OFF_RB  = OFF_BC  + (size_t)1088 * 1536 * 2;// u16[400*768]
constexpr size_t OFF_PC  = OFF_RB  + (size_t)400 * 768 * 2;  // f32[400*300]
constexpr size_t OFF_B3P = OFF_PC  + (size_t)400 * 300 * 4;  // f32[16*768] bs3 partials
constexpr size_t OFF_B3  = OFF_B3P + 16 * 768 * 4;           // f32[768] bs3
constexpr size_t OFF_BSC = OFF_B3  + 768 * 4;                // f32[300] bsC

// ================= K1: weight prep (Wot, Wct, Wpd, u, bs3 partials, W3partial) =================
__global__ __launch_bounds__(256) void k_prep(
    const float* __restrict__ W_start, const float* __restrict__ b_start,
    const float* __restrict__ W_end, const float* __restrict__ b_end,
    const float* __restrict__ wemb, const float* __restrict__ W_out,
    const float* __restrict__ b_out, const float* __restrict__ w_men,
    const float* __restrict__ W_p1, char* __restrict__ ws) {
  unsigned short* Wot = (unsigned short*)(ws + OFF_WOT);
  unsigned short* Wct = (unsigned short*)(ws + OFF_WCT);
  unsigned short* Wpd = (unsigned short*)(ws + OFF_WPD);
  double* u   = (double*)(ws + OFF_U);
  float*  W3p = (float*)(ws + OFF_W3);
  float*  b3P = (float*)(ws + OFF_B3P);
  int blk = blockIdx.x, t = threadIdx.x;
  int wv = t >> 6, lane = t & 63;
  __shared__ float Tl[32][33];
  int rr = t >> 5, cc = t & 31;
  // W_out transpose -> Wot [768][1568] bf16
  for (int j = blk; j < 49 * 24; j += 512) {
    int k0 = (j % 49) * 32, n0 = (j / 49) * 32;
    #pragma unroll
    for (int q = 0; q < 4; ++q) {
      int kr = rr + q * 8, kk = k0 + kr;
      Tl[kr][cc] = (kk < FDIM) ? W_out[(size_t)kk * HDIM + n0 + cc] : 0.f;
    }
    __syncthreads();
    #pragma unroll
    for (int q = 0; q < 4; ++q) {
      int nr = rr + q * 8;
      Wot[(size_t)(n0 + nr) * FPAD + k0 + cc] = f2b(Tl[cc][nr]);
    }
    __syncthreads();
  }
  // Wct [320][768], Wpd [160][768]
  for (int idx = blk * 256 + t; idx < 480 * HDIM; idx += 512 * 256) {
    if (idx < 320 * HDIM) {
      int n = idx / HDIM, h = idx % HDIM;
      float v = 0.f;
      if (n < PHID)      v = W_p1[(size_t)h * PHID + n] + W_p1[(size_t)(2 * HDIM + h) * PHID + n];
      else if (n < 300)  v = W_p1[(size_t)(HDIM + h) * PHID + (n - PHID)] -
                             W_p1[(size_t)(2 * HDIM + h) * PHID + (n - PHID)];
      Wct[idx] = f2b(v);
    } else {
      int j = idx - 320 * HDIM;
      int n = j / HDIM, h = j % HDIM;
      Wpd[j] = f2b((n < PHID) ? W_p1[(size_t)(3 * HDIM + h) * PHID + n] : 0.f);
    }
  }
  // u = W_out @ w_men (fp64 exact) — blocks 0..391
  {
    int wg = blk * 4 + wv;
    if (wg < FDIM) {
      const float* Wrow = W_out + (size_t)wg * HDIM;
      double acc = 0.0;
      for (int c = lane; c < HDIM; c += 64) acc += (double)Wrow[c] * (double)w_men[c];
      for (int off = 32; off; off >>= 1) acc += __shfl_down(acc, off);
      if (!lane) u[wg] = acc;
    }
  }
  // bs3 partials — blocks 448..495 (16 c-chunks x 3 n-chunks, 96-deep loops)
  if (blk >= 448 && blk < 496) {
    int cb = blk - 448;
    int cchunk = cb >> 2;          // 0..11? no: 48 blocks = 16 cchunk * 3 nchunk
    cchunk = cb / 3;
    int nchunk = cb % 3;
    int n = nchunk * 256 + t;
    float acc = 0.f;
    int c0 = cchunk * 48;
    for (int c = c0; c < c0 + 48; ++c)
      acc += b_start[c] * W_out[(size_t)c * HDIM + n] +
             b_end[c]   * W_out[(size_t)(HDIM + c) * HDIM + n];
    b3P[cchunk * HDIM + n] = acc;
  }
  // W3partial[w][n] = b_out[n] + sum_d wemb[w][d]*W_out[(2H+d)][n] — blocks 496..511
  if (blk >= 496) {
    for (int idx = (blk - 496) * 256 + t; idx < NW * HDIM; idx += 16 * 256) {
      int w = idx / HDIM, n = idx % HDIM;
      float acc = b_out[n];
      #pragma unroll 5
      for (int d = 0; d < WDIM; ++d)
        acc += wemb[w * WDIM + d] * W_out[(size_t)(2 * HDIM + d) * HDIM + n];
      W3p[idx] = acc;
    }
  }
}

// ================= K2: M1/M2 GEMMs + vs/ve/mwc + W3C' + bs3 finalize =================
__global__ __launch_bounds__(256) void k_mid(
    const float* __restrict__ W_start, const float* __restrict__ W_end,
    const float* __restrict__ b_start, const float* __restrict__ b_end,
    const float* __restrict__ b_out, const float* __restrict__ w_men,
    const float* __restrict__ b_men, const float* __restrict__ wemb,
    char* __restrict__ ws) {
  unsigned short* Wot = (unsigned short*)(ws + OFF_WOT);
  unsigned short* Wct = (unsigned short*)(ws + OFF_WCT);
  unsigned short* M1  = (unsigned short*)(ws + OFF_M1);
  unsigned short* M2  = (unsigned short*)(ws + OFF_M2);
  unsigned short* Bc  = (unsigned short*)(ws + OFF_BC);
  double* u   = (double*)(ws + OFF_U);
  float*  vs  = (float*)(ws + OFF_VS);
  float*  ve  = (float*)(ws + OFF_VE);
  double* mwc = (double*)(ws + OFF_MWC);
  float*  W3p = (float*)(ws + OFF_W3);
  float*  W3C = (float*)(ws + OFF_W3C);
  float*  b3P = (float*)(ws + OFF_B3P);
  float*  bs3 = (float*)(ws + OFF_B3);
  int blk = blockIdx.x, t = threadIdx.x;
  int wv = t >> 6, lane = t & 63, quad = lane >> 4, coll = lane & 15;
  int rs = t >> 2, ch = t & 3;
  __shared__ short Al[64 * LSTR];
  __shared__ short Bl[64 * LSTR];

  if (blk < 288) {
    bool isM2 = blk >= 144;
    int tau = isM2 ? blk - 144 : blk;
    int Mt = (tau % 12) * 64, Nt = (tau / 12) * 64;
    const float* A = isM2 ? W_end : W_start;
    int koff = isM2 ? HDIM : 0;
    unsigned short* Mnt = isM2 ? M2 : M1;
    const float* asrc = A + (size_t)(Mt + rs) * HDIM + ch * 8;
    const unsigned short* bsrc = Wot + (size_t)(Nt + rs) * FPAD + koff + ch * 8;
    f32x4 acc[4];
    #pragma unroll
    for (int i = 0; i < 4; ++i) acc[i] = {0.f, 0.f, 0.f, 0.f};
    float4 ax = *(const float4*)asrc, ay = *(const float4*)(asrc + 4);
    u16x8 bx = *(const u16x8*)bsrc;
    for (int it = 0; it < 24; ++it) {
      bf16x8 pk;
      pk[0]=(short)f2b(ax.x); pk[1]=(short)f2b(ax.y); pk[2]=(short)f2b(ax.z); pk[3]=(short)f2b(ax.w);
      pk[4]=(short)f2b(ay.x); pk[5]=(short)f2b(ay.y); pk[6]=(short)f2b(ay.z); pk[7]=(short)f2b(ay.w);
      *(bf16x8*)&Al[rs * LSTR + ch * 8] = pk;
      *(u16x8*)&Bl[rs * LSTR + ch * 8] = bx;
      __syncthreads();
      if (it < 23) {
        ax = *(const float4*)(asrc + (it + 1) * 32);
        ay = *(const float4*)(asrc + (it + 1) * 32 + 4);
        bx = *(const u16x8*)(bsrc + (it + 1) * 32);
      }
      bf16x8 a = *(bf16x8*)&Al[(wv * 16 + coll) * LSTR + quad * 8];
      #pragma unroll
      for (int ct = 0; ct < 4; ++ct) {
        bf16x8 bfr = *(bf16x8*)&Bl[(ct * 16 + coll) * LSTR + quad * 8];
        acc[ct] = __builtin_amdgcn_mfma_f32_16x16x32_bf16(a, bfr, acc[ct], 0, 0, 0);
      }
      __syncthreads();
    }
    #pragma unroll
    for (int ct = 0; ct < 4; ++ct) {
      int n = Nt + ct * 16 + coll;
      #pragma unroll
      for (int reg = 0; reg < 4; ++reg) {
        int h = Mt + wv * 16 + quad * 4 + reg;
        unsigned short v = f2b(acc[ct][reg]);
        Bc[(size_t)n * 1536 + koff + h] = v;
        Mnt[(size_t)h * HDIM + n] = v;
      }
    }
  } else if (blk < 673) {
    int wg = (blk - 288) * 4 + wv;
    if (wg < HDIM) {
      const float* Wrow = W_start + (size_t)wg * HDIM;
      double acc = 0.0;
      for (int j = lane; j < HDIM; j += 64) acc += (double)Wrow[j] * u[j];
      for (int off = 32; off; off >>= 1) acc += __shfl_down(acc, off);
      if (!lane) vs[wg] = (float)acc;
    } else if (wg < 2 * HDIM) {
      int r = wg - HDIM;
      const float* Wrow = W_end + (size_t)r * HDIM;
      double acc = 0.0;
      for (int j = lane; j < HDIM; j += 64) acc += (double)Wrow[j] * u[HDIM + j];
      for (int off = 32; off; off >>= 1) acc += __shfl_down(acc, off);
      if (!lane) ve[r] = (float)acc;
    } else if (wg == 2 * HDIM) {
      double acc = 0.0;
      for (int j = lane; j < HDIM; j += 64)
        acc += (double)b_start[j] * u[j] + (double)b_end[j] * u[HDIM + j] +
               (double)b_out[j] * (double)w_men[j];
      for (int off = 32; off; off >>= 1) acc += __shfl_down(acc, off);
      if (!lane) mwc[11] = acc + (double)b_men[0];
      if (lane < NW) {
        double a = 0.0;
        for (int d = 0; d < WDIM; ++d) a += (double)wemb[lane * WDIM + d] * u[2 * HDIM + d];
        mwc[lane] = a;
      }
    }
  } else if (blk < 1498) {
    // W3C'[w][p] = sum_c W3partial[w][c] * Wct[p][c]
    int oid = (blk - 673) * 4 + wv;
    if (oid < NW * 300) {
      int w = oid / 300, p = oid % 300;
      const float* w3r = W3p + (size_t)w * HDIM;
      const unsigned short* wcr = Wct + (size_t)p * HDIM;
      float acc = 0.f;
      for (int c = lane; c < HDIM; c += 64) acc += w3r[c] * b2f(wcr[c]);
      for (int off = 32; off; off >>= 1) acc += __shfl_down(acc, off);
      if (!lane) W3C[w * 300 + p] = acc;
    }
  } else {
    // bs3 finalize: sum 16 partials
    int n = (blk - 1498) * 256 + t;
    if (n < HDIM) {
      float acc = 0.f;
      #pragma unroll
      for (int k = 0; k < 16; ++k) acc += b3P[k * HDIM + n];
      bs3[n] = acc;
    }
  }
}

// ================= K3: token scores (fp64 exact) + M1C/M2C chain GEMMs + bsC =================
__global__ __launch_bounds__(256) void k_tok(const float* __restrict__ seq,
                                             char* __restrict__ ws) {
  double* ms = (double*)(ws + OFF_MS);
  double* me = (double*)(ws + OFF_ME);
  const float* vs = (const float*)(ws + OFF_VS);
  const float* ve = (const float*)(ws + OFF_VE);
  unsigned short* Wct = (unsigned short*)(ws + OFF_WCT);
  unsigned short* M1  = (unsigned short*)(ws + OFF_M1);
  unsigned short* M2  = (unsigned short*)(ws + OFF_M2);
  unsigned short* Bc  = (unsigned short*)(ws + OFF_BC);
  const float* bs3 = (const float*)(ws + OFF_B3);
  float* bsC = (float*)(ws + OFF_BSC);
  int blk = blockIdx.x, t = threadIdx.x;
  int wv = t >> 6, lane = t & 63, quad = lane >> 4, coll = lane & 15;
  int rs = t >> 2, ch = t & 3;
  __shared__ short Al[64 * LSTR];
  __shared__ short Bl[64 * LSTR];

  if (blk < 8192) {
    int row = blk * 4 + wv;
    const float4* p  = (const float4*)(seq + (size_t)row * HDIM);
    const float4* pa = (const float4*)vs;
    const float4* pb = (const float4*)ve;
    double as = 0.0, ae = 0.0;
    #pragma unroll
    for (int k = 0; k < 3; ++k) {
      float4 x = p[lane + 64 * k];
      float4 a = pa[lane + 64 * k];
      float4 b = pb[lane + 64 * k];
      as += (double)x.x * a.x + (double)x.y * a.y + (double)x.z * a.z + (double)x.w * a.w;
      ae += (double)x.x * b.x + (double)x.y * b.y + (double)x.z * b.z + (double)x.w * b.w;
    }
    for (int off = 32; off; off >>= 1) { as += __shfl_down(as, off); ae += __shfl_down(ae, off); }
    if (!lane) { ms[row] = as; me[row] = ae; }
  } else if (blk < 8312) {
    int cb = blk - 8192;
    bool isM2C = cb >= 60;
    int tau = isM2C ? cb - 60 : cb;
    int Mt = (tau / 12) * 64, Nt = (tau % 12) * 64;
    const unsigned short* Mnt = isM2C ? M2 : M1;
    int koff = isM2C ? HDIM : 0;
    const unsigned short* asrc = Wct + (size_t)(Mt + rs) * HDIM + ch * 8;
    const unsigned short* bsrc = Mnt + (size_t)(Nt + rs) * HDIM + ch * 8;
    f32x4 acc[4];
    #pragma unroll
    for (int i = 0; i < 4; ++i) acc[i] = {0.f, 0.f, 0.f, 0.f};
    u16x8 axv = *(const u16x8*)asrc;
    u16x8 bxv = *(const u16x8*)bsrc;
    for (int it = 0; it < 24; ++it) {
      *(u16x8*)&Al[rs * LSTR + ch * 8] = axv;
      *(u16x8*)&Bl[rs * LSTR + ch * 8] = bxv;
      __syncthreads();
      if (it < 23) {
        axv = *(const u16x8*)(asrc + (it + 1) * 32);
        bxv = *(const u16x8*)(bsrc + (it + 1) * 32);
      }
      bf16x8 a = *(bf16x8*)&Al[(wv * 16 + coll) * LSTR + quad * 8];
      #pragma unroll
      for (int ct = 0; ct < 4; ++ct) {
        bf16x8 bfr = *(bf16x8*)&Bl[(ct * 16 + coll) * LSTR + quad * 8];
        acc[ct] = __builtin_amdgcn_mfma_f32_16x16x32_bf16(a, bfr, acc[ct], 0, 0, 0);
      }
      __syncthreads();
    }
    #pragma unroll
    for (int ct = 0; ct < 4; ++ct) {
      int h = Nt + ct * 16 + coll;
      #pragma unroll
      for (int reg = 0; reg < 4; ++reg) {
        int p = Mt + wv * 16 + quad * 4 + reg;
        Bc[(size_t)(768 + p) * 1536 + koff + h] = f2b(acc[ct][reg]);
      }
    }
  } else {
    // bsC[p] = sum_c bs3[c] * Wct[p][c]
    int oid = (blk - 8312) * 4 + wv;
    if (oid < 300) {
      const unsigned short* wcr = Wct + (size_t)oid * HDIM;
      float acc = 0.f;
      for (int c = lane; c < HDIM; c += 64) acc += bs3[c] * b2f(wcr[c]);
      for (int off = 32; off; off >>= 1) acc += __shfl_down(acc, off);
      if (!lane) bsC[oid] = acc;
    }
  }
}

// ================= K4: mention scores + top-50 (radix select, exact tie-break) =================
__global__ __launch_bounds__(1024) void k_topk(
    const int* __restrict__ st, const int* __restrict__ en, char* __restrict__ ws,
    float* __restrict__ out_top) {
  const double* ms  = (const double*)(ws + OFF_MS);
  const double* me  = (const double*)(ws + OFF_ME);
  const double* mwc = (const double*)(ws + OFF_MWC);
  int* sel_s = (int*)(ws + OFF_SS);
  int* sel_e = (int*)(ws + OFF_SE);
  int* sel_w = (int*)(ws + OFF_SW);
  int b = blockIdx.x, t = threadIdx.x;
  int wave = t >> 6, lane = t & 63;
  __shared__ unsigned hist[16][256];
  __shared__ unsigned histc[256], hist2[256];
  __shared__ int s_T1, s_G1, s_T2;
  __shared__ unsigned s_cnt;
  __shared__ float sval[SURV_CAP];
  __shared__ int   sidx[SURV_CAP];

  for (int i = t; i < 16 * 256; i += 1024) ((unsigned*)hist)[i] = 0;
  if (t < 256) { histc[t] = 0; hist2[t] = 0; }
  if (t == 0) s_cnt = 0;
  double c0 = mwc[11];
  float v[8]; unsigned key[8];
  #pragma unroll
  for (int i = 0; i < 8; ++i) {
    int gi = b * NSPAN + i * 1024 + t;
    int s = st[gi], e = en[gi];
    int w = e - s; w = w < 0 ? 0 : (w > NW - 1 ? NW - 1 : w);
    v[i] = (float)(ms[b * SDIM + s] + me[b * SDIM + e] + mwc[w] + c0);
    union { float f; unsigned u; } x; x.f = v[i];
    key[i] = (x.u >> 31) ? ~x.u : (x.u | 0x80000000u);
  }
  __syncthreads();
  #pragma unroll
  for (int i = 0; i < 8; ++i) atomicAdd(&hist[wave][key[i] >> 24], 1u);
  __syncthreads();
  if (t < 256) {
    unsigned c = 0;
    #pragma unroll
    for (int g = 0; g < 16; ++g) c += hist[g][t];
    histc[t] = c;
  }
  __syncthreads();
  if (t < 64) {
    unsigned suf = histc[4 * lane] + histc[4 * lane + 1] + histc[4 * lane + 2] + histc[4 * lane + 3];
    #pragma unroll
    for (int off = 1; off < 64; off <<= 1) {
      unsigned o = __shfl_down(suf, off);
      if (lane + off < 64) suf += o;
    }
    unsigned long long mk = __ballot(suf >= 50u);
    int g = 63 - __builtin_clzll(mk);
    unsigned cab = __shfl(suf, g < 63 ? g + 1 : 63);
    if (g == 63) cab = 0;
    if (lane == 0) {
      unsigned cg = cab; int T1 = 4 * g;
      for (int k = 3; k >= 0; --k) {
        unsigned c = histc[4 * g + k];
        if (cg + c >= 50u) { T1 = 4 * g + k; break; }
        cg += c;
      }
      s_T1 = T1; s_G1 = (int)cg;
    }
  }
  __syncthreads();
  int T1 = s_T1;
  unsigned target = 50u - (unsigned)s_G1;
  #pragma unroll
  for (int i = 0; i < 8; ++i)
    if ((int)(key[i] >> 24) == T1) atomicAdd(&hist2[(key[i] >> 16) & 255], 1u);
  __syncthreads();
  if (t < 64) {
    unsigned suf = hist2[4 * lane] + hist2[4 * lane + 1] + hist2[4 * lane + 2] + hist2[4 * lane + 3];
    #pragma unroll
    for (int off = 1; off < 64; off <<= 1) {
      unsigned o = __shfl_down(suf, off);
      if (lane + off < 64) suf += o;
    }
    unsigned long long mk = __ballot(suf >= target);
    int g = 63 - __builtin_clzll(mk);
    unsigned cab = __shfl(suf, g < 63 ? g + 1 : 63);
    if (g == 63) cab = 0;
    if (lane == 0) {
      unsigned cg = cab; int T2 = 4 * g;
      for (int k = 3; k >= 0; --k) {
        unsigned c = hist2[4 * g + k];
        if (cg + c >= target) { T2 = 4 * g + k; break; }
        cg += c;
      }
      s_T2 = T2;
    }
  }
  __syncthreads();
  unsigned thr16 = ((unsigned)T1 << 8) | (unsigned)s_T2;
  #pragma unroll
  for (int i = 0; i < 8; ++i) {
    if ((key[i] >> 16) >= thr16) {
      unsigned p = atomicAdd(&s_cnt, 1u);
      if (p < SURV_CAP) { sval[p] = v[i]; sidx[p] = i * 1024 + t; }
    }
  }
  __syncthreads();
  int n = s_cnt < SURV_CAP ? (int)s_cnt : SURV_CAP;
  for (int m = t; m < n; m += 1024) {
    float mv = sval[m]; int mi = sidx[m];
    int rank = 0;
    for (int s = 0; s < n; ++s) {
      float ov = sval[s]; int oi = sidx[s];
      rank += (ov > mv || (ov == mv && oi < mi)) ? 1 : 0;
    }
    if (rank < TK) {
      out_top[b * TK + rank] = mv;
      int gi = b * NSPAN + mi;
      int s0 = st[gi], e0 = en[gi];
      int w = e0 - s0; w = w < 0 ? 0 : (w > NW - 1 ? NW - 1 : w);
      sel_s[b * TK + rank] = s0; sel_e[b * TK + rank] = e0; sel_w[b * TK + rank] = w;
    }
  }
}

// ================= K5: fused span gather-GEMM (K=1536, N=1088) =================
__global__ __launch_bounds__(256) void k_span(const float* __restrict__ seq,
                                              char* __restrict__ ws) {
  const int* sel_s = (const int*)(ws + OFF_SS);
  const int* sel_e = (const int*)(ws + OFF_SE);
  const int* sel_w = (const int*)(ws + OFF_SW);
  const float* W3p = (const float*)(ws + OFF_W3);
  const float* W3C = (const float*)(ws + OFF_W3C);
  const float* bs3 = (const float*)(ws + OFF_B3);
  const float* bsC = (const float*)(ws + OFF_BSC);
  unsigned short* Bc = (unsigned short*)(ws + OFF_BC);
  unsigned short* Rb = (unsigned short*)(ws + OFF_RB);
  float* Pcat = (float*)(ws + OFF_PC);
  int blk = blockIdx.x, t = threadIdx.x;
  int wv = t >> 6, lane = t & 63, quad = lane >> 4, coll = lane & 15;
  int rs = t >> 2, ch = t & 3;
  __shared__ short Al[64 * LSTR];
  __shared__ short Bl[64 * LSTR];

  int Mt = (blk / 17) * 64, Nt = (blk % 17) * 64;
  int r0 = Mt + rs;
  int rr2 = r0 < 400 ? r0 : 0;
  int bb = rr2 / TK;
  const float* ps = seq + ((size_t)bb * SDIM + sel_s[rr2]) * HDIM;
  const float* pe = seq + ((size_t)bb * SDIM + sel_e[rr2]) * HDIM;
  const unsigned short* bsrc = Bc + (size_t)(Nt + rs) * 1536 + ch * 8;
  f32x4 acc[4];
  #pragma unroll
  for (int i = 0; i < 4; ++i) acc[i] = {0.f, 0.f, 0.f, 0.f};
  int kg0 = ch * 8;
  const float* s0p = (kg0 < HDIM ? ps : pe) + (kg0 & (HDIM - 1));
  float4 ax = *(const float4*)s0p, ay = *(const float4*)(s0p + 4);
  u16x8 bx = *(const u16x8*)bsrc;
  for (int it = 0; it < 48; ++it) {
    bf16x8 pk;
    pk[0]=(short)f2b(ax.x); pk[1]=(short)f2b(ax.y); pk[2]=(short)f2b(ax.z); pk[3]=(short)f2b(ax.w);
    pk[4]=(short)f2b(ay.x); pk[5]=(short)f2b(ay.y); pk[6]=(short)f2b(ay.z); pk[7]=(short)f2b(ay.w);
    *(bf16x8*)&Al[rs * LSTR + ch * 8] = pk;
    *(u16x8*)&Bl[rs * LSTR + ch * 8] = bx;
    __syncthreads();
    if (it < 47) {
      int kg = (it + 1) * 32 + ch * 8;
      const float* sp = (kg < HDIM ? ps : pe) + (kg & (HDIM - 1));
      ax = *(const float4*)sp; ay = *(const float4*)(sp + 4);
      bx = *(const u16x8*)(bsrc + (it + 1) * 32);
    }
    bf16x8 a = *(bf16x8*)&Al[(wv * 16 + coll) * LSTR + quad * 8];
    #pragma unroll
    for (int ct = 0; ct < 4; ++ct) {
      bf16x8 bfr = *(bf16x8*)&Bl[(ct * 16 + coll) * LSTR + quad * 8];
      acc[ct] = __builtin_amdgcn_mfma_f32_16x16x32_bf16(a, bfr, acc[ct], 0, 0, 0);
    }
    __syncthreads();
  }
  #pragma unroll
  for (int reg = 0; reg < 4; ++reg) {
    int r = Mt + wv * 16 + quad * 4 + reg;
    if (r < 400) {
      int w = sel_w[r];
      #pragma unroll
      for (int ct = 0; ct < 4; ++ct) {
        int c = Nt + ct * 16 + coll;
        if (c < HDIM) {
          Rb[(size_t)r * HDIM + c] = f2b(acc[ct][reg] + W3p[(size_t)w * HDIM + c] + bs3[c]);
        } else if (c < HDIM + 300) {
          int p = c - HDIM;
          Pcat[(size_t)r * 300 + p] = acc[ct][reg] + W3C[w * 300 + p] + bsC[p];
        }
      }
    }
  }
}

// ================= K6: pair scorer + ant fill + mask =================
__global__ __launch_bounds__(256) void k_pair(
    const float* __restrict__ bp1, const float* __restrict__ g,
    const float* __restrict__ bb_, const float* __restrict__ wp2,
    const float* __restrict__ bp2, float* __restrict__ out, char* __restrict__ ws) {
  const unsigned short* Rb  = (const unsigned short*)(ws + OFF_RB);
  const unsigned short* Wpd = (const unsigned short*)(ws + OFF_WPD);
  const float* Pcat = (const float*)(ws + OFF_PC);
  int blk = blockIdx.x, t = threadIdx.x;
  int ptile = blk % 40, b = blk / 40;
  int wv = t >> 6, lane = t & 63, quad = lane >> 4, coll = lane & 15;
  int rs = t >> 2, ch = t & 3;
  float* ant  = out + 400;
  float* mask = out + 400 + BATCH * TK * TK;
  __shared__ short Al[64 * LSTR];
  __shared__ short Bl[160 * LSTR];
  f32x4 acc[10];
  #pragma unroll
  for (int i = 0; i < 10; ++i) acc[i] = {0.f, 0.f, 0.f, 0.f};

  int pr_s = ptile * 64 + rs; if (pr_s >= 2500) pr_s = 0;
  const unsigned short* Ri = Rb + ((size_t)b * TK + pr_s / TK) * HDIM;
  const unsigned short* Rj = Rb + ((size_t)b * TK + pr_s % TK) * HDIM;
  int bi0 = t, bi1 = t + 256, bi2 = t + 512;
  u16x8 ri = *(const u16x8*)(Ri + ch * 8);
  u16x8 rj = *(const u16x8*)(Rj + ch * 8);
  u16x8 bw0, bw1, bw2;
  bw0 = *(const u16x8*)(Wpd + (size_t)(bi0 >> 2) * HDIM + (bi0 & 3) * 8);
  bw1 = *(const u16x8*)(Wpd + (size_t)(bi1 >> 2) * HDIM + (bi1 & 3) * 8);
  if (bi2 < 640) bw2 = *(const u16x8*)(Wpd + (size_t)(bi2 >> 2) * HDIM + (bi2 & 3) * 8);

  for (int it = 0; it < 24; ++it) {
    {
      bf16x8 pk;
      #pragma unroll
      for (int q = 0; q < 8; ++q) pk[q] = (short)f2b(b2f(ri[q]) * b2f(rj[q]));
      *(bf16x8*)&Al[rs * LSTR + ch * 8] = pk;
    }
    *(u16x8*)&Bl[(bi0 >> 2) * LSTR + (bi0 & 3) * 8] = bw0;
    *(u16x8*)&Bl[(bi1 >> 2) * LSTR + (bi1 & 3) * 8] = bw1;
    if (bi2 < 640) *(u16x8*)&Bl[(bi2 >> 2) * LSTR + (bi2 & 3) * 8] = bw2;
    __syncthreads();
    if (it < 23) {
      int kk = (it + 1) * 32;
      ri = *(const u16x8*)(Ri + kk + ch * 8);
      rj = *(const u16x8*)(Rj + kk + ch * 8);
      bw0 = *(const u16x8*)(Wpd + (size_t)(bi0 >> 2) * HDIM + kk + (bi0 & 3) * 8);
      bw1 = *(const u16x8*)(Wpd + (size_t)(bi1 >> 2) * HDIM + kk + (bi1 & 3) * 8);
      if (bi2 < 640) bw2 = *(const u16x8*)(Wpd + (size_t)(bi2 >> 2) * HDIM + kk + (bi2 & 3) * 8);
    }
    bf16x8 a = *(bf16x8*)&Al[(wv * 16 + coll) * LSTR + quad * 8];
    #pragma unroll
    for (int ct = 0; ct < 10; ++ct) {
      bf16x8 bfr = *(bf16x8*)&Bl[(ct * 16 + coll) * LSTR + quad * 8];
      acc[ct] = __builtin_amdgcn_mfma_f32_16x16x32_bf16(a, bfr, acc[ct], 0, 0, 0);
    }
    __syncthreads();
  }

  float gc[10], bbc[10], w2c[10], b1c[10];
  #pragma unroll
  for (int ct = 0; ct < 10; ++ct) {
    int c = ct * 16 + coll;
    bool vv2 = c < PHID;
    gc[ct] = vv2 ? g[c] : 0.f; bbc[ct] = vv2 ? bb_[c] : 0.f;
    w2c[ct] = vv2 ? wp2[c] : 0.f; b1c[ct] = vv2 ? bp1[c] : 0.f;
  }
  float bp2v = bp2[0];

  #pragma unroll
  for (int reg = 0; reg < 4; ++reg) {
    int pr = ptile * 64 + wv * 16 + quad * 4 + reg;
    if (pr < 2500) {
      int i = pr / TK, j = pr % TK;
      float d = 0.f;
      if (j < i) {
        const float* Pi = Pcat + (size_t)(b * TK + i) * 300;
        const float* Pj = Pcat + (size_t)(b * TK + j) * 300 + PHID;
        float rr[10]; float sum = 0.f, sumsq = 0.f;
        #pragma unroll
        for (int ct = 0; ct < 10; ++ct) {
          int c = ct * 16 + coll;
          float v = 0.f;
          if (c < PHID) {
            v = acc[ct][reg] + Pi[c] + Pj[c] + b1c[ct];
            v = v > 0.f ? v : 0.f;
          }
          rr[ct] = v; sum += v; sumsq += v * v;
        }
        #pragma unroll
        for (int off = 1; off < 16; off <<= 1) {
          sum   += __shfl_xor(sum, off);
          sumsq += __shfl_xor(sumsq, off);
        }
        float mu  = sum * (1.f / PHID);
        float var = sumsq * (1.f / PHID) - mu * mu;
        float inv = rsqrtf(var + 1e-5f);
        #pragma unroll
        for (int ct = 0; ct < 10; ++ct)
          d += ((rr[ct] - mu) * inv * gc[ct] + bbc[ct]) * w2c[ct];
        #pragma unroll
        for (int off = 1; off < 16; off <<= 1) d += __shfl_xor(d, off);
        d += bp2v;
      }
      if (coll == 0) ant[(size_t)b * 2500 + pr] = (j < i) ? d : 0.0f;
    }
  }
  if (b == 0 && t < 64) {
    int pr = ptile * 64 + t;
    if (pr < 2500) mask[pr] = ((pr % TK) < (pr / TK)) ? 1.0f : 0.0f;
  }
}

// ============================ launch ============================

extern "C" void kernel_launch(void* const* d_in, const int* in_sizes, int n_in,
                              void* d_out, int out_size, void* d_ws, size_t ws_size,
                              hipStream_t stream) {
  const float* seq     = (const float*)d_in[0];
  const int*   sp_st   = (const int*)d_in[1];
  const int*   sp_en   = (const int*)d_in[2];
  const float* W_start = (const float*)d_in[3];
  const float* b_start = (const float*)d_in[4];
  const float* W_end   = (const float*)d_in[5];
  const float* b_end   = (const float*)d_in[6];
  const float* wemb    = (const float*)d_in[7];
  const float* W_out   = (const float*)d_in[8];
  const float* b_out   = (const float*)d_in[9];
  const float* w_men   = (const float*)d_in[10];
  const float* b_men   = (const float*)d_in[11];
  const float* W_p1    = (const float*)d_in[12];
  const float* b_p1    = (const float*)d_in[13];
  const float* ln_g    = (const float*)d_in[14];
  const float* ln_b    = (const float*)d_in[15];
  const float* W_p2    = (const float*)d_in[16];
  const float* b_p2    = (const float*)d_in[17];
  char* ws = (char*)d_ws;
  float* out = (float*)d_out;

  k_prep<<<dim3(512), dim3(256), 0, stream>>>(W_start, b_start, W_end, b_end, wemb,
                                              W_out, b_out, w_men, W_p1, ws);
  k_mid<<<dim3(1501), dim3(256), 0, stream>>>(W_start, W_end, b_start, b_end,
                                              b_out, w_men, b_men, wemb, ws);
  k_tok<<<dim3(8387), dim3(256), 0, stream>>>(seq, ws);
  k_topk<<<dim3(BATCH), dim3(1024), 0, stream>>>(sp_st, sp_en, ws, out);
  k_span<<<dim3(119), dim3(256), 0, stream>>>(seq, ws);
  k_pair<<<dim3(320), dim3(256), 0, stream>>>(b_p1, ln_g, ln_b, W_p2, b_p2, out, ws);
}